// Round 1
// baseline (2132.187 us; speedup 1.0000x reference)
//
#include <hip/hip_runtime.h>

#define NB 32
#define NS 48
#define NL 48
#define NH 1024
#define NE 1024
#define NV 32000
#define NR (NS*NB)      // 1536
#define K3H 3072
#define NBLK_R 256
#define THR_R 512

typedef unsigned short u16;
typedef __bf16 bf16x8 __attribute__((ext_vector_type(8)));
typedef unsigned short ushort8 __attribute__((ext_vector_type(8)));
typedef float f32x4 __attribute__((ext_vector_type(4)));

__device__ __forceinline__ float bf2f(u16 x) {
    union { unsigned u; float f; } c; c.u = ((unsigned)x) << 16; return c.f;
}
__device__ __forceinline__ u16 f2bf(float f) {
    union { float f; unsigned u; } c; c.f = f;
    unsigned r = (c.u + 0x7FFFu + ((c.u >> 16) & 1u)) >> 16;
    return (u16)r;
}
__device__ __forceinline__ f32x4 mfma16(bf16x8 a, bf16x8 b, f32x4 c) {
    return __builtin_amdgcn_mfma_f32_16x16x32_bf16(a, b, c, 0, 0, 0);
}
__device__ __forceinline__ void gld_lds16(const void* g, void* l) {
    __builtin_amdgcn_global_load_lds((const __attribute__((address_space(1))) void*)g,
                                     (__attribute__((address_space(3))) void*)l, 16, 0, 0);
}

// ---------------- transpose + cast: dst[n][k] = src[k][n] ----------------
__global__ __launch_bounds__(256) void transpose_cast(const float* __restrict__ src, int K, int N,
                                                      char* __restrict__ dst, int bf16out) {
    __shared__ float tile[32][33];
    int k0 = blockIdx.y * 32, n0 = blockIdx.x * 32;
    int tx = threadIdx.x & 31, ty = threadIdx.x >> 5;
    for (int i = 0; i < 4; ++i) {
        int n = n0 + tx;
        float v = (n < N) ? src[(size_t)(k0 + ty + i*8) * N + n] : 0.f;
        tile[ty + i*8][tx] = v;
    }
    __syncthreads();
    for (int i = 0; i < 4; ++i) {
        int n = n0 + ty + i*8;
        int k = k0 + tx;
        if (n < N) {
            float v = tile[tx][ty + i*8];
            if (bf16out) ((u16*)dst)[(size_t)n * K + k] = f2bf(v);
            else         ((float*)dst)[(size_t)n * K + k] = v;
        }
    }
}

// ---------------- prep: xe=relu(emb[label]) -> bf16; enc -> bf16; init_h -> bf16 ----------------
__global__ __launch_bounds__(256) void prep_inputs(const int* __restrict__ label, const float* __restrict__ emb,
                                                   const float* __restrict__ enc, const float* __restrict__ inith,
                                                   u16* __restrict__ xe, u16* __restrict__ encb, u16* __restrict__ hinit) {
    int blk = blockIdx.x, t = threadIdx.x;
    if (blk < NR) {
        int s = blk >> 5, b = blk & 31;
        int lab = label[b * NS + s];
        const float* src = emb + (size_t)lab * NE;
        u16* dst = xe + (size_t)blk * NE;
        for (int i = t; i < NE; i += 256) { float v = src[i]; dst[i] = f2bf(v > 0.f ? v : 0.f); }
    } else if (blk < 2 * NR) {
        int r = blk - NR;
        const float* src = enc + (size_t)r * NH;
        u16* dst = encb + (size_t)r * NH;
        for (int i = t; i < NH; i += 256) dst[i] = f2bf(src[i]);
    } else {
        int b = blk - 2 * NR;
        const float* src = inith + (size_t)b * NH;
        u16* dst = hinit + (size_t)b * NH;
        for (int i = t; i < NH; i += 256) dst[i] = f2bf(src[i]);
    }
}

// ---------------- simxe[r][l] = xe[r,:] @ attn_W[0:1024, l] + attn_b[l] ----------------
__global__ __launch_bounds__(64) void simxe_kernel(const u16* __restrict__ xe, const float* __restrict__ attnW,
                                                   const float* __restrict__ attnB, float* __restrict__ simxe) {
    int r = blockIdx.x, t = threadIdx.x;
    if (t >= NL) return;
    const u16* x = xe + (size_t)r * NE;
    float acc = attnB[t];
    for (int k = 0; k < NE; ++k) acc += bf2f(x[k]) * attnW[(size_t)k * NL + t];
    simxe[(size_t)r * NL + t] = acc;
}

// ---------------- bf16 MFMA GEMM, 128x128 tile, BK=64, K=1024 fixed ----------------
// A: [M][1024] bf16 row-major.  Bt: [N][1024] bf16 (i.e. B transposed).
// MODE 0: float C[m*N+n];  MODE 1: decoder layout d_out[(m&31)*NS + (m>>5)][n];  MODE 2: bf16 C[m*N+n]
template<int MODE>
__global__ __launch_bounds__(256) void gemm_bf16(const u16* __restrict__ A, const u16* __restrict__ Bt,
                                                 void* __restrict__ Cout, const float* __restrict__ bias, int N) {
    __shared__ u16 ldsA[128 * 64];
    __shared__ u16 ldsB[128 * 64];
    const int t = threadIdx.x;
    const int lane = t & 63, w = t >> 6;
    const int wm = w >> 1, wn = w & 1;
    const int m0 = blockIdx.x * 128, n0 = blockIdx.y * 128;
    f32x4 acc[4][4] = {};
    for (int kt = 0; kt < 16; ++kt) {
        const int k0 = kt * 64;
#pragma unroll
        for (int i = 0; i < 4; ++i) {
            int chunk = i * 256 + t;
            int row = chunk >> 3, slot = chunk & 7;
            int srck = ((slot ^ (row & 7)) * 8);
            const u16* ga = A  + (size_t)(m0 + row) * 1024 + k0 + srck;
            const u16* gb = Bt + (size_t)(n0 + row) * 1024 + k0 + srck;
            u16* la = ldsA + (size_t)(i * 256 + w * 64) * 8;
            u16* lb = ldsB + (size_t)(i * 256 + w * 64) * 8;
            gld_lds16(ga, la);
            gld_lds16(gb, lb);
        }
        asm volatile("s_waitcnt vmcnt(0)" ::: "memory");
        __syncthreads();
#pragma unroll
        for (int kk = 0; kk < 2; ++kk) {
            bf16x8 a[4], b[4];
#pragma unroll
            for (int f = 0; f < 4; ++f) {
                int rowA = wm * 64 + f * 16 + (lane & 15);
                int slotA = (kk * 4 + (lane >> 4)) ^ (rowA & 7);
                a[f] = *reinterpret_cast<const bf16x8*>(ldsA + rowA * 64 + slotA * 8);
                int rowB = wn * 64 + f * 16 + (lane & 15);
                int slotB = (kk * 4 + (lane >> 4)) ^ (rowB & 7);
                b[f] = *reinterpret_cast<const bf16x8*>(ldsB + rowB * 64 + slotB * 8);
            }
#pragma unroll
            for (int fm = 0; fm < 4; ++fm)
#pragma unroll
                for (int fn = 0; fn < 4; ++fn)
                    acc[fm][fn] = mfma16(a[fm], b[fn], acc[fm][fn]);
        }
        __syncthreads();
    }
#pragma unroll
    for (int fm = 0; fm < 4; ++fm) {
#pragma unroll
        for (int fn = 0; fn < 4; ++fn) {
#pragma unroll
            for (int rr = 0; rr < 4; ++rr) {
                int m = m0 + wm * 64 + fm * 16 + (lane >> 4) * 4 + rr;
                int n = n0 + wn * 64 + fn * 16 + (lane & 15);
                float v = acc[fm][fn][rr];
                if (bias) v += bias[n];
                if (MODE == 0)      ((float*)Cout)[(size_t)m * N + n] = v;
                else if (MODE == 2) ((u16*)Cout)[(size_t)m * N + n] = f2bf(v);
                else {
                    ((float*)Cout)[((size_t)(m & 31) * NS + (m >> 5)) * NV + n] = v;
                }
            }
        }
    }
}

// ---------------- grid barrier (device scope, sense via generation counter) ----------------
__device__ __forceinline__ void gbar(int* bar) {
    __syncthreads();
    if (threadIdx.x == 0) {
        int g = __hip_atomic_load(&bar[64], __ATOMIC_RELAXED, __HIP_MEMORY_SCOPE_AGENT);
        int prev = __hip_atomic_fetch_add(&bar[0], 1, __ATOMIC_ACQ_REL, __HIP_MEMORY_SCOPE_AGENT);
        if (prev == NBLK_R - 1) {
            __hip_atomic_store(&bar[0], 0, __ATOMIC_RELAXED, __HIP_MEMORY_SCOPE_AGENT);
            __hip_atomic_store(&bar[64], g + 1, __ATOMIC_RELEASE, __HIP_MEMORY_SCOPE_AGENT);
        } else {
            int guard = 0;
            while (__hip_atomic_load(&bar[64], __ATOMIC_RELAXED, __HIP_MEMORY_SCOPE_AGENT) == g) {
                __builtin_amdgcn_s_sleep(2);
                if (++guard > (1 << 26)) break;   // safety: degrade to wrong answer, not hang
            }
            __builtin_amdgcn_fence(__ATOMIC_ACQUIRE, "agent");
        }
    }
    __syncthreads();
}

// ---------------- persistent sequential recurrence ----------------
// 256 blocks x 512 threads, 1 block/CU (122KB LDS). 48 steps x 3 grid barriers.
// Stage A: blocks 0..47 sim col l + softmax over batch; blocks 64..255 gh = h@W_hh + b_hh (MFMA)
// Stage B: all 256 blocks: g[b][jslice] = relu(sum_l w[b,l]*P_lds[l][j] + gxe)
// Stage C: blocks 0..63: gx (3 gate tiles x 2 m-tiles MFMA) + GRU gates + h_new -> hall[s]
__global__ __launch_bounds__(THR_R) void recurrence(
    const u16* __restrict__ hinit, const float* __restrict__ simxe, const u16* __restrict__ gxe,
    const u16* __restrict__ P, const float* __restrict__ aw2t,
    const u16* __restrict__ whht, const u16* __restrict__ wiht,
    const float* __restrict__ b_ih, const float* __restrict__ b_hh,
    float* __restrict__ w_att, float* __restrict__ gh, u16* __restrict__ gbf,
    u16* __restrict__ hall, int* __restrict__ bar) {

    __shared__ __align__(16) char smem_all[122368];
    u16*   P_lds   = (u16*)(smem_all + 0);          // [48][128] bf16 = 12288B
    float* w_lds   = (float*)(smem_all + 12288);    // 48 floats
    float* sim_lds = (float*)(smem_all + 12544);    // 32 floats
    float* W2T_lds = (float*)(smem_all + 12672);    // 1088 floats (swizzle-padded)
    float* gx_lds  = (float*)(smem_all + 17024);    // [3][32][16] f32 = 6144B
    u16*   WT_lds  = (u16*)(smem_all + 23168);      // gx: [3][16][1032]; gh blocks alias: [16][1032]

    const int blk = blockIdx.x, t = threadIdx.x;
    const int b_my = blk >> 3, jc = blk & 7;

    // ---- one-time preloads (step-invariant) ----
    for (int idx = t; idx < 48 * 128; idx += THR_R) {
        int l = idx >> 7, j = idx & 127;
        P_lds[idx] = P[((size_t)(b_my * 48 + l)) * NH + jc * 128 + j];
    }
    if (blk < 48) {
        for (int k = t; k < 1024; k += THR_R)
            W2T_lds[k + ((k >> 6) << 2)] = aw2t[(size_t)blk * 1024 + k];
    }
    if (blk < 64) {
        for (int g = 0; g < 3; ++g) {
            const u16* src = wiht + ((size_t)(g * 1024 + 16 * blk)) * 1024;
            for (int idx = t; idx < 16 * 1024; idx += THR_R) {
                int col = idx >> 10, k = idx & 1023;
                WT_lds[(size_t)g * 16 * 1032 + col * 1032 + k] = src[(size_t)col * 1024 + k];
            }
        }
    } else {
        int j2 = blk - 64;
        const u16* src = whht + ((size_t)(16 * j2)) * 1024;
        for (int idx = t; idx < 16 * 1024; idx += THR_R) {
            int col = idx >> 10, k = idx & 1023;
            WT_lds[col * 1032 + k] = src[(size_t)col * 1024 + k];
        }
    }
    __syncthreads();

    for (int s = 0; s < NS; ++s) {
        const u16* hprev = (s == 0) ? hinit : (hall + (size_t)(s - 1) * NB * NH);

        // ================= STAGE A =================
        if (blk < 48) {
            const int l = blk;
            const int bb = t >> 4, kp = t & 15;
            const u16* hrow = hprev + (size_t)bb * NH + kp * 64;
            const float* wb = W2T_lds + kp * 68;
            float partial = 0.f;
#pragma unroll
            for (int jj = 0; jj < 8; ++jj) {
                ushort8 hv = *reinterpret_cast<const ushort8*>(hrow + jj * 8);
                f32x4 w0 = *reinterpret_cast<const f32x4*>(wb + jj * 8);
                f32x4 w1 = *reinterpret_cast<const f32x4*>(wb + jj * 8 + 4);
#pragma unroll
                for (int u = 0; u < 4; ++u) partial += bf2f(hv[u]) * w0[u];
#pragma unroll
                for (int u = 0; u < 4; ++u) partial += bf2f(hv[u + 4]) * w1[u];
            }
            partial += __shfl_xor(partial, 1);
            partial += __shfl_xor(partial, 2);
            partial += __shfl_xor(partial, 4);
            partial += __shfl_xor(partial, 8);
            if (kp == 0) sim_lds[bb] = partial;
            __syncthreads();
            if (t < 32) {
                float sv = sim_lds[t] + simxe[((size_t)(s * 32 + t)) * NL + l];
                float m = sv;
                for (int o = 16; o >= 1; o >>= 1) m = fmaxf(m, __shfl_xor(m, o));
                float e = __expf(sv - m);
                float sum = e;
                for (int o = 16; o >= 1; o >>= 1) sum += __shfl_xor(sum, o);
                w_att[(size_t)t * NL + l] = e / sum;
            }
        } else if (blk >= 64) {
            int j2 = blk - 64;
            int wv = t >> 6, lane = t & 63;
            if (wv < 2) {
                int m0 = wv * 16;
                int r = lane & 15, kg = lane >> 4;
                const u16* aPtr = hprev + (size_t)(m0 + r) * NH + kg * 8;
                const u16* wrow = WT_lds + r * 1032 + kg * 8;
                f32x4 acc0 = {}, acc1 = {};
#pragma unroll
                for (int k = 0; k < 1024; k += 64) {
                    bf16x8 av0 = *reinterpret_cast<const bf16x8*>(aPtr + k);
                    bf16x8 bv0 = *reinterpret_cast<const bf16x8*>(wrow + k);
                    acc0 = mfma16(av0, bv0, acc0);
                    bf16x8 av1 = *reinterpret_cast<const bf16x8*>(aPtr + k + 32);
                    bf16x8 bv1 = *reinterpret_cast<const bf16x8*>(wrow + k + 32);
                    acc1 = mfma16(av1, bv1, acc1);
                }
#pragma unroll
                for (int rr = 0; rr < 4; ++rr) {
                    int bb = m0 + kg * 4 + rr;
                    int c = 16 * j2 + r;
                    gh[(size_t)bb * K3H + c] = acc0[rr] + acc1[rr] + b_hh[c];
                }
            }
        }
        gbar(bar);

        // ================= STAGE B =================
        if (t < 48) w_lds[t] = w_att[(size_t)b_my * NL + t];
        __syncthreads();
        if (t < 128) {
            int j = jc * 128 + t;
            float acc = bf2f(gxe[((size_t)(s * 32 + b_my)) * NH + j]);  // includes comb_b (GEMM bias)
#pragma unroll
            for (int l = 0; l < 48; ++l)
                acc += w_lds[l] * bf2f(P_lds[l * 128 + t]);
            acc = fmaxf(acc, 0.f);
            gbf[(size_t)b_my * NH + j] = f2bf(acc);
        }
        gbar(bar);

        // ================= STAGE C =================
        if (blk < 64) {
            int wv = t >> 6, lane = t & 63;
            if (wv < 6) {
                int gate = wv >> 1, mt = wv & 1;
                int m0 = mt * 16;
                int r = lane & 15, kg = lane >> 4;
                const u16* aPtr = gbf + (size_t)(m0 + r) * NH + kg * 8;
                const u16* wrow = WT_lds + (size_t)gate * 16 * 1032 + r * 1032 + kg * 8;
                f32x4 acc0 = {}, acc1 = {};
#pragma unroll
                for (int k = 0; k < 1024; k += 64) {
                    bf16x8 av0 = *reinterpret_cast<const bf16x8*>(aPtr + k);
                    bf16x8 bv0 = *reinterpret_cast<const bf16x8*>(wrow + k);
                    acc0 = mfma16(av0, bv0, acc0);
                    bf16x8 av1 = *reinterpret_cast<const bf16x8*>(aPtr + k + 32);
                    bf16x8 bv1 = *reinterpret_cast<const bf16x8*>(wrow + k + 32);
                    acc1 = mfma16(av1, bv1, acc1);
                }
#pragma unroll
                for (int rr = 0; rr < 4; ++rr)
                    gx_lds[(gate * 32 + m0 + kg * 4 + rr) * 16 + r] = acc0[rr] + acc1[rr];
            }
            __syncthreads();
            {
                int bb = t >> 4, il = t & 15;
                int i = 16 * blk + il;
                float xr = gx_lds[(0 * 32 + bb) * 16 + il] + b_ih[i];
                float xz = gx_lds[(1 * 32 + bb) * 16 + il] + b_ih[1024 + i];
                float xn = gx_lds[(2 * 32 + bb) * 16 + il] + b_ih[2048 + i];
                float hr = gh[(size_t)bb * K3H + i];
                float hz = gh[(size_t)bb * K3H + 1024 + i];
                float hn = gh[(size_t)bb * K3H + 2048 + i];
                float rg = 1.f / (1.f + __expf(-(xr + hr)));
                float zg = 1.f / (1.f + __expf(-(xz + hz)));
                float ng = tanhf(xn + rg * hn);
                float hold = bf2f(hprev[(size_t)bb * NH + i]);
                float hnew = (1.f - zg) * ng + zg * hold;
                hall[((size_t)s * NB + bb) * NH + i] = f2bf(hnew);
            }
        }
        gbar(bar);
    }
}

// ---------------- in-place log_softmax per row of d_out ----------------
__global__ __launch_bounds__(256) void logsoftmax_kernel(float* __restrict__ out) {
    __shared__ float red[8];
    float* row = out + (size_t)blockIdx.x * NV;
    int t = threadIdx.x;
    float m = -1e30f;
    for (int i = t; i < NV; i += 256) m = fmaxf(m, row[i]);
    for (int o = 32; o >= 1; o >>= 1) m = fmaxf(m, __shfl_xor(m, o));
    if ((t & 63) == 0) red[t >> 6] = m;
    __syncthreads();
    m = fmaxf(fmaxf(red[0], red[1]), fmaxf(red[2], red[3]));
    float sum = 0.f;
    for (int i = t; i < NV; i += 256) sum += __expf(row[i] - m);
    for (int o = 32; o >= 1; o >>= 1) sum += __shfl_xor(sum, o);
    if ((t & 63) == 0) red[4 + (t >> 6)] = sum;
    __syncthreads();
    sum = (red[4] + red[5]) + (red[6] + red[7]);
    float lse = m + __logf(sum);
    for (int i = t; i < NV; i += 256) row[i] = row[i] - lse;
}

extern "C" void kernel_launch(void* const* d_in, const int* in_sizes, int n_in,
                              void* d_out, int out_size, void* d_ws, size_t ws_size,
                              hipStream_t stream) {
    const int*   label = (const int*)  d_in[0];
    const float* inith = (const float*)d_in[1];
    const float* enc   = (const float*)d_in[2];
    const float* emb   = (const float*)d_in[3];
    const float* attnW = (const float*)d_in[4];
    const float* attnB = (const float*)d_in[5];
    const float* combW = (const float*)d_in[6];
    const float* combB = (const float*)d_in[7];
    const float* Wih   = (const float*)d_in[8];
    const float* Whh   = (const float*)d_in[9];
    const float* bih   = (const float*)d_in[10];
    const float* bhh   = (const float*)d_in[11];
    const float* outW  = (const float*)d_in[12];
    const float* outB  = (const float*)d_in[13];
    char* ws = (char*)d_ws;

    // workspace carve (bytes)
    size_t BAR_OFF   = 0;                               // 512
    size_t OUTWT_OFF = 512;                             // 65,536,000  bf16 [V][H]
    size_t WHHT_OFF  = OUTWT_OFF + (size_t)NV*NH*2;     // 6,291,456   bf16 [3H][H]
    size_t WIHT_OFF  = WHHT_OFF + (size_t)K3H*NH*2;     // 6,291,456   bf16 [3H][H]
    size_t CW1T_OFF  = WIHT_OFF + (size_t)K3H*NH*2;     // 2,097,152   bf16 [H][H]
    size_t CW2T_OFF  = CW1T_OFF + (size_t)NH*NH*2;      // 2,097,152   bf16 [H][H]
    size_t AW2T_OFF  = CW2T_OFF + (size_t)NH*NH*2;      // 196,608     f32  [L][H]
    size_t XE_OFF    = AW2T_OFF + (size_t)NL*NH*4;      // 3,145,728   bf16 [1536][E]
    size_t ENCB_OFF  = XE_OFF   + (size_t)NR*NE*2;      // 3,145,728   bf16 [1536][H]
    size_t SIMXE_OFF = ENCB_OFF + (size_t)NR*NH*2;      // 294,912     f32  [1536][L]
    size_t GXE_OFF   = SIMXE_OFF+ (size_t)NR*NL*4;      // 3,145,728   bf16 [1536][H]
    size_t P_OFF     = GXE_OFF  + (size_t)NR*NH*2;      // 3,145,728   bf16 [1536][H]
    size_t HALL_OFF  = P_OFF    + (size_t)NR*NH*2;      // 3,145,728   bf16 [S][B][H]
    size_t HINIT_OFF = HALL_OFF + (size_t)NR*NH*2;      // 65,536      bf16 [B][H]
    size_t WATT_OFF  = HINIT_OFF+ (size_t)NB*NH*2;      // 6,144       f32  [B][L]
    size_t GH_OFF    = WATT_OFF + (size_t)NB*NL*4;      // 393,216     f32  [B][3H]
    size_t GBF_OFF   = GH_OFF   + (size_t)NB*K3H*4;     // 65,536      bf16 [B][H]

    int*   bar   = (int*)(ws + BAR_OFF);
    u16*   outWT = (u16*)(ws + OUTWT_OFF);
    u16*   whht  = (u16*)(ws + WHHT_OFF);
    u16*   wiht  = (u16*)(ws + WIHT_OFF);
    u16*   cw1t  = (u16*)(ws + CW1T_OFF);
    u16*   cw2t  = (u16*)(ws + CW2T_OFF);
    float* aw2t  = (float*)(ws + AW2T_OFF);
    u16*   xe    = (u16*)(ws + XE_OFF);
    u16*   encb  = (u16*)(ws + ENCB_OFF);
    float* simxe = (float*)(ws + SIMXE_OFF);
    u16*   gxe   = (u16*)(ws + GXE_OFF);
    u16*   Pb    = (u16*)(ws + P_OFF);
    u16*   hall  = (u16*)(ws + HALL_OFF);
    u16*   hinit = (u16*)(ws + HINIT_OFF);
    float* watt  = (float*)(ws + WATT_OFF);
    float* ghb   = (float*)(ws + GH_OFF);
    u16*   gbfb  = (u16*)(ws + GBF_OFF);

    hipMemsetAsync(bar, 0, 512, stream);
    prep_inputs<<<2 * NR + NB, 256, 0, stream>>>(label, emb, enc, inith, xe, encb, hinit);

    transpose_cast<<<dim3(NV / 32, 32), 256, 0, stream>>>(outW, NH, NV, (char*)outWT, 1);
    transpose_cast<<<dim3(K3H / 32, 32), 256, 0, stream>>>(Whh, NH, K3H, (char*)whht, 1);
    transpose_cast<<<dim3(K3H / 32, 32), 256, 0, stream>>>(Wih, NH, K3H, (char*)wiht, 1);
    transpose_cast<<<dim3(NH / 32, 32), 256, 0, stream>>>(combW, NH, NH, (char*)cw1t, 1);
    transpose_cast<<<dim3(NH / 32, 32), 256, 0, stream>>>(combW + (size_t)NH * NH, NH, NH, (char*)cw2t, 1);
    transpose_cast<<<dim3(2, 32), 256, 0, stream>>>(attnW + (size_t)NH * NL, NH, NL, (char*)aw2t, 0);

    simxe_kernel<<<NR, 64, 0, stream>>>(xe, attnW, attnB, simxe);
    gemm_bf16<2><<<dim3(NR / 128, NH / 128), 256, 0, stream>>>(xe, cw2t, gxe, combB, NH);
    gemm_bf16<2><<<dim3(NR / 128, NH / 128), 256, 0, stream>>>(encb, cw1t, Pb, nullptr, NH);

    recurrence<<<NBLK_R, THR_R, 0, stream>>>(hinit, simxe, gxe, Pb, aw2t, whht, wiht,
                                             bih, bhh, watt, ghb, gbfb, hall, bar);

    gemm_bf16<1><<<dim3(NR / 128, NV / 128), 256, 0, stream>>>(hall, outWT, d_out, outB, NV);
    logsoftmax_kernel<<<NR, 256, 0, stream>>>((float*)d_out);
}

// Round 2
// 1487.004 us; speedup vs baseline: 1.4339x; 1.4339x over previous
//
#include <hip/hip_runtime.h>

#define NB 32
#define NS 48
#define NL 48
#define NH 1024
#define NE 1024
#define NV 32000
#define NR (NS*NB)      // 1536
#define K3H 3072
#define RA_BLOCKS 64
#define RB_BLOCKS 128
#define NBLK_R2 (RA_BLOCKS + RB_BLOCKS)

typedef unsigned short u16;
typedef __bf16 bf16x8 __attribute__((ext_vector_type(8)));
typedef unsigned short ushort8 __attribute__((ext_vector_type(8)));
typedef float f32x4 __attribute__((ext_vector_type(4)));

__device__ __forceinline__ float bf2f(u16 x) {
    union { unsigned u; float f; } c; c.u = ((unsigned)x) << 16; return c.f;
}
__device__ __forceinline__ u16 f2bf(float f) {
    union { float f; unsigned u; } c; c.f = f;
    unsigned r = (c.u + 0x7FFFu + ((c.u >> 16) & 1u)) >> 16;
    return (u16)r;
}
__device__ __forceinline__ f32x4 mfma16(bf16x8 a, bf16x8 b, f32x4 c) {
    return __builtin_amdgcn_mfma_f32_16x16x32_bf16(a, b, c, 0, 0, 0);
}
__device__ __forceinline__ void gld_lds16(const void* g, void* l) {
    __builtin_amdgcn_global_load_lds((const __attribute__((address_space(1))) void*)g,
                                     (__attribute__((address_space(3))) void*)l, 16, 0, 0);
}

// ---------------- transpose + cast: dst[n][k] = src[k][n] ----------------
__global__ __launch_bounds__(256) void transpose_cast(const float* __restrict__ src, int K, int N,
                                                      char* __restrict__ dst, int bf16out) {
    __shared__ float tile[32][33];
    int k0 = blockIdx.y * 32, n0 = blockIdx.x * 32;
    int tx = threadIdx.x & 31, ty = threadIdx.x >> 5;
    for (int i = 0; i < 4; ++i) {
        int n = n0 + tx;
        float v = (n < N) ? src[(size_t)(k0 + ty + i*8) * N + n] : 0.f;
        tile[ty + i*8][tx] = v;
    }
    __syncthreads();
    for (int i = 0; i < 4; ++i) {
        int n = n0 + ty + i*8;
        int k = k0 + tx;
        if (n < N) {
            float v = tile[tx][ty + i*8];
            if (bf16out) ((u16*)dst)[(size_t)n * K + k] = f2bf(v);
            else         ((float*)dst)[(size_t)n * K + k] = v;
        }
    }
}

// ---------------- prep: xe=relu(emb[label]) -> bf16; enc -> bf16; init_h -> hallx[0] ----------------
__global__ __launch_bounds__(256) void prep_inputs(const int* __restrict__ label, const float* __restrict__ emb,
                                                   const float* __restrict__ enc, const float* __restrict__ inith,
                                                   u16* __restrict__ xe, u16* __restrict__ encb, u16* __restrict__ hallx) {
    int blk = blockIdx.x, t = threadIdx.x;
    if (blk < NR) {
        int s = blk >> 5, b = blk & 31;
        int lab = label[b * NS + s];
        const float* src = emb + (size_t)lab * NE;
        u16* dst = xe + (size_t)blk * NE;
        for (int i = t; i < NE; i += 256) { float v = src[i]; dst[i] = f2bf(v > 0.f ? v : 0.f); }
    } else if (blk < 2 * NR) {
        int r = blk - NR;
        const float* src = enc + (size_t)r * NH;
        u16* dst = encb + (size_t)r * NH;
        for (int i = t; i < NH; i += 256) dst[i] = f2bf(src[i]);
    } else {
        int b = blk - 2 * NR;
        const float* src = inith + (size_t)b * NH;
        u16* dst = hallx + (size_t)b * NH;   // slot 0 = h_{-1}
        for (int i = t; i < NH; i += 256) dst[i] = f2bf(src[i]);
    }
}

// ---------------- simxe[r][l] = xe[r,:] @ attn_W1^T[l,:] + attn_b[l] ----------------
__global__ __launch_bounds__(384) void simxe2_kernel(const u16* __restrict__ xe, const u16* __restrict__ aw1t,
                                                     const float* __restrict__ attnB, float* __restrict__ simxe) {
    int r = blockIdx.x, t = threadIdx.x;
    int l = t >> 3, part = t & 7;
    const u16* x = xe + (size_t)r * 1024 + part * 128;
    const u16* ww = aw1t + (size_t)l * 1024 + part * 128;
    float acc = 0.f;
#pragma unroll
    for (int k = 0; k < 128; k += 8) {
        ushort8 xv = *reinterpret_cast<const ushort8*>(x + k);
        ushort8 wv = *reinterpret_cast<const ushort8*>(ww + k);
#pragma unroll
        for (int u = 0; u < 8; ++u) acc += bf2f(xv[u]) * bf2f(wv[u]);
    }
    acc += __shfl_xor(acc, 1);
    acc += __shfl_xor(acc, 2);
    acc += __shfl_xor(acc, 4);
    if (part == 0) simxe[(size_t)r * NL + l] = acc + attnB[l];
}

// ---------------- bf16 MFMA GEMM, 128x128 tile, BK=64, K=1024 fixed ----------------
template<int MODE>
__global__ __launch_bounds__(256) void gemm_bf16(const u16* __restrict__ A, const u16* __restrict__ Bt,
                                                 void* __restrict__ Cout, const float* __restrict__ bias, int N) {
    __shared__ u16 ldsA[128 * 64];
    __shared__ u16 ldsB[128 * 64];
    const int t = threadIdx.x;
    const int lane = t & 63, w = t >> 6;
    const int wm = w >> 1, wn = w & 1;
    const int m0 = blockIdx.x * 128, n0 = blockIdx.y * 128;
    f32x4 acc[4][4] = {};
    for (int kt = 0; kt < 16; ++kt) {
        const int k0 = kt * 64;
#pragma unroll
        for (int i = 0; i < 4; ++i) {
            int chunk = i * 256 + t;
            int row = chunk >> 3, slot = chunk & 7;
            int srck = ((slot ^ (row & 7)) * 8);
            const u16* ga = A  + (size_t)(m0 + row) * 1024 + k0 + srck;
            const u16* gb = Bt + (size_t)(n0 + row) * 1024 + k0 + srck;
            u16* la = ldsA + (size_t)(i * 256 + w * 64) * 8;
            u16* lb = ldsB + (size_t)(i * 256 + w * 64) * 8;
            gld_lds16(ga, la);
            gld_lds16(gb, lb);
        }
        asm volatile("s_waitcnt vmcnt(0)" ::: "memory");
        __syncthreads();
#pragma unroll
        for (int kk = 0; kk < 2; ++kk) {
            bf16x8 a[4], b[4];
#pragma unroll
            for (int f = 0; f < 4; ++f) {
                int rowA = wm * 64 + f * 16 + (lane & 15);
                int slotA = (kk * 4 + (lane >> 4)) ^ (rowA & 7);
                a[f] = *reinterpret_cast<const bf16x8*>(ldsA + rowA * 64 + slotA * 8);
                int rowB = wn * 64 + f * 16 + (lane & 15);
                int slotB = (kk * 4 + (lane >> 4)) ^ (rowB & 7);
                b[f] = *reinterpret_cast<const bf16x8*>(ldsB + rowB * 64 + slotB * 8);
            }
#pragma unroll
            for (int fm = 0; fm < 4; ++fm)
#pragma unroll
                for (int fn = 0; fn < 4; ++fn)
                    acc[fm][fn] = mfma16(a[fm], b[fn], acc[fm][fn]);
        }
        __syncthreads();
    }
#pragma unroll
    for (int fm = 0; fm < 4; ++fm) {
#pragma unroll
        for (int fn = 0; fn < 4; ++fn) {
#pragma unroll
            for (int rr = 0; rr < 4; ++rr) {
                int m = m0 + wm * 64 + fm * 16 + (lane >> 4) * 4 + rr;
                int n = n0 + wn * 64 + fn * 16 + (lane & 15);
                float v = acc[fm][fn][rr];
                if (bias) v += bias[n];
                if (MODE == 0)      ((float*)Cout)[(size_t)m * N + n] = v;
                else if (MODE == 2) ((u16*)Cout)[(size_t)m * N + n] = f2bf(v);
                else {
                    ((float*)Cout)[((size_t)(m & 31) * NS + (m >> 5)) * NV + n] = v;
                }
            }
        }
    }
}

// ---------------- flag sync primitives (device scope) ----------------
__device__ __forceinline__ void wait_ge(int* flag, int tgt) {
    int guard = 0;
    while (__hip_atomic_load(flag, __ATOMIC_RELAXED, __HIP_MEMORY_SCOPE_AGENT) < tgt) {
        __builtin_amdgcn_s_sleep(2);
        if (++guard > (1 << 25)) break;   // safety valve: wrong answer, not hang
    }
    __builtin_amdgcn_fence(__ATOMIC_ACQUIRE, "agent");
}
__device__ __forceinline__ void arrive(int* cnt, int* flag, int total, int step) {
    int prev = __hip_atomic_fetch_add(cnt, 1, __ATOMIC_ACQ_REL, __HIP_MEMORY_SCOPE_AGENT);
    if (prev == total * (step + 1) - 1)
        __hip_atomic_store(flag, step + 1, __ATOMIC_RELEASE, __HIP_MEMORY_SCOPE_AGENT);
}

// ---------------- persistent recurrence, role-split, 2 flag epochs/step ----------------
// Role A (blocks 0..63): b=blk>>1, half=blk&1. Redundant full sim via MFMA (+simxe as acc
//   init), softmax over batch, g[b][half] -> g_glob (bf16). LDS: W2^T[48][1032] + P-slice.
// Role B (blocks 64..191): 8 h-cols each. gh (after h ready) then gx (after g ready) via
//   MFMA with A from global, B from LDS-resident 24-col weight slices; gates; h -> hallx[s+1].
// Flags: C1/F1 = role-A done (g ready); C2/F2 = role-B done (h ready).
__global__ __launch_bounds__(512) void recurrence2(
    const float* __restrict__ simxe, const u16* __restrict__ gxe,
    const u16* __restrict__ P, const u16* __restrict__ aw2t,
    const u16* __restrict__ whht, const u16* __restrict__ wiht,
    const float* __restrict__ b_ih, const float* __restrict__ b_hh,
    u16* __restrict__ g_glob, u16* __restrict__ hallx, int* __restrict__ bar)
{
    __shared__ __align__(16) char smem[154624];
    int* C1 = bar + 0;  int* F1 = bar + 32;
    int* C2 = bar + 64; int* F2 = bar + 96;
    const int blk = blockIdx.x, t = threadIdx.x;
    const int lane = t & 63, w = t >> 6;
    const int r16 = lane & 15, kg = lane >> 4;

    if (blk < RA_BLOCKS) {
        // =========== ROLE A ===========
        const int b = blk >> 1, half = blk & 1;
        u16*   W2T  = (u16*)smem;                    // [48][1032] bf16
        u16*   Pl   = (u16*)(smem + 99072);          // [48][512] bf16
        float* siml = (float*)(smem + 148224);       // [32][48] f32
        float* wl   = (float*)(smem + 154368);       // [48] f32
        for (int idx = t; idx < 48 * 1024; idx += 512) {
            int l = idx >> 10, k = idx & 1023;
            W2T[l * 1032 + k] = aw2t[idx];
        }
        for (int idx = t; idx < 48 * 512; idx += 512) {
            int l = idx >> 9, j = idx & 511;
            Pl[idx] = P[((size_t)(b * 48 + l)) * NH + half * 512 + j];
        }
        __syncthreads();

        for (int s = 0; s < NS; ++s) {
            if (t == 0) wait_ge(F2, s);
            __syncthreads();
            const u16* hprev = hallx + (size_t)s * (NB * NH);
            // --- sim = h @ W2 (+ simxe via acc init): 6 waves, tiles (mt in 0..1, nt in 0..2)
            if (w < 6) {
                const int mt = w & 1, nt = w >> 1;
                const int m0 = mt * 16, n0 = nt * 16;
                f32x4 acc0; f32x4 acc1 = {};
                const float* sxe = simxe + (size_t)(s * 32) * NL;
#pragma unroll
                for (int rr = 0; rr < 4; ++rr)
                    acc0[rr] = sxe[(m0 + kg * 4 + rr) * NL + n0 + r16];
                const u16* aP = hprev + (size_t)(m0 + r16) * NH + kg * 8;
                const u16* bP = W2T + (n0 + r16) * 1032 + kg * 8;
#pragma unroll 4
                for (int k = 0; k < 1024; k += 64) {
                    acc0 = mfma16(*reinterpret_cast<const bf16x8*>(aP + k),
                                  *reinterpret_cast<const bf16x8*>(bP + k), acc0);
                    acc1 = mfma16(*reinterpret_cast<const bf16x8*>(aP + k + 32),
                                  *reinterpret_cast<const bf16x8*>(bP + k + 32), acc1);
                }
#pragma unroll
                for (int rr = 0; rr < 4; ++rr)
                    siml[(m0 + kg * 4 + rr) * NL + n0 + r16] = acc0[rr] + acc1[rr];
            }
            __syncthreads();
            // --- softmax over batch (col-wise), keep only row b
            if (t < NL) {
                float m = -1e30f;
                for (int b2 = 0; b2 < NB; ++b2) m = fmaxf(m, siml[b2 * NL + t]);
                float den = 0.f;
                for (int b2 = 0; b2 < NB; ++b2) den += __expf(siml[b2 * NL + t] - m);
                wl[t] = __expf(siml[b * NL + t] - m) / den;
            }
            __syncthreads();
            // --- g[b][half*512 + t] = relu(gxe + sum_l wl[l]*P[l][t])
            {
                float acc = bf2f(gxe[((size_t)(s * 32 + b)) * NH + half * 512 + t]);
#pragma unroll
                for (int l = 0; l < 48; ++l) acc += wl[l] * bf2f(Pl[l * 512 + t]);
                g_glob[b * NH + half * 512 + t] = f2bf(fmaxf(acc, 0.f));
            }
            __syncthreads();
            if (t == 0) arrive(C1, F1, RA_BLOCKS, s);
        }
    } else {
        // =========== ROLE B ===========
        const int c0 = (blk - RA_BLOCKS) * 8;
        u16*   Whh = (u16*)smem;                     // [32][1032] bf16 (rows 24..31 zero)
        u16*   Wih = (u16*)(smem + 66048);           // [32][1032] bf16
        float* ghs = (float*)(smem + 132096);        // [2][32][32] f32
        float* gxs = (float*)(smem + 140288);        // [2][32][32] f32
        for (int idx = t; idx < 32 * 1024; idx += 512) {
            int pr = idx >> 10, k = idx & 1023;
            u16 vh = 0, vi = 0;
            if (pr < 24) {
                size_t srow = (size_t)((pr >> 3) * 1024 + c0 + (pr & 7));
                vh = whht[srow * NH + k];
                vi = wiht[srow * NH + k];
            }
            Whh[pr * 1032 + k] = vh;
            Wih[pr * 1032 + k] = vi;
        }
        __syncthreads();
        const int mt = (w >> 1) & 1, nt = w & 1, kh = w >> 2;
        const int m0 = mt * 16;

        for (int s = 0; s < NS; ++s) {
            if (t == 0) wait_ge(F2, s);
            __syncthreads();
            const u16* hprev = hallx + (size_t)s * (NB * NH);
            // --- gh = h @ W_hh slice (8 waves: 2m x 2n x 2k-halves)
            {
                f32x4 acc0 = {}, acc1 = {};
                const u16* aP = hprev + (size_t)(m0 + r16) * NH + kh * 512 + kg * 8;
                const u16* bP = Whh + (nt * 16 + r16) * 1032 + kh * 512 + kg * 8;
#pragma unroll 4
                for (int k = 0; k < 512; k += 64) {
                    acc0 = mfma16(*reinterpret_cast<const bf16x8*>(aP + k),
                                  *reinterpret_cast<const bf16x8*>(bP + k), acc0);
                    acc1 = mfma16(*reinterpret_cast<const bf16x8*>(aP + k + 32),
                                  *reinterpret_cast<const bf16x8*>(bP + k + 32), acc1);
                }
#pragma unroll
                for (int rr = 0; rr < 4; ++rr)
                    ghs[kh * 1024 + (m0 + kg * 4 + rr) * 32 + nt * 16 + r16] = acc0[rr] + acc1[rr];
            }
            if (t == 0) wait_ge(F1, s + 1);
            __syncthreads();
            // --- gx = g @ W_ih slice
            {
                f32x4 acc0 = {}, acc1 = {};
                const u16* aP = g_glob + (size_t)(m0 + r16) * NH + kh * 512 + kg * 8;
                const u16* bP = Wih + (nt * 16 + r16) * 1032 + kh * 512 + kg * 8;
#pragma unroll 4
                for (int k = 0; k < 512; k += 64) {
                    acc0 = mfma16(*reinterpret_cast<const bf16x8*>(aP + k),
                                  *reinterpret_cast<const bf16x8*>(bP + k), acc0);
                    acc1 = mfma16(*reinterpret_cast<const bf16x8*>(aP + k + 32),
                                  *reinterpret_cast<const bf16x8*>(bP + k + 32), acc1);
                }
#pragma unroll
                for (int rr = 0; rr < 4; ++rr)
                    gxs[kh * 1024 + (m0 + kg * 4 + rr) * 32 + nt * 16 + r16] = acc0[rr] + acc1[rr];
            }
            __syncthreads();
            // --- gates + h_new for (32 batches x 8 cols)
            if (t < 256) {
                int b2 = t >> 3, col = t & 7;
                float gxr = gxs[b2 * 32 + col]      + gxs[1024 + b2 * 32 + col]      + b_ih[c0 + col];
                float gxz = gxs[b2 * 32 + 8 + col]  + gxs[1024 + b2 * 32 + 8 + col]  + b_ih[1024 + c0 + col];
                float gxn = gxs[b2 * 32 + 16 + col] + gxs[1024 + b2 * 32 + 16 + col] + b_ih[2048 + c0 + col];
                float ghr = ghs[b2 * 32 + col]      + ghs[1024 + b2 * 32 + col]      + b_hh[c0 + col];
                float ghz = ghs[b2 * 32 + 8 + col]  + ghs[1024 + b2 * 32 + 8 + col]  + b_hh[1024 + c0 + col];
                float ghn = ghs[b2 * 32 + 16 + col] + ghs[1024 + b2 * 32 + 16 + col] + b_hh[2048 + c0 + col];
                float rg = 1.f / (1.f + __expf(-(gxr + ghr)));
                float zg = 1.f / (1.f + __expf(-(gxz + ghz)));
                float ng = tanhf(gxn + rg * ghn);
                float hold = bf2f(hprev[b2 * NH + c0 + col]);
                float hnew = (1.f - zg) * ng + zg * hold;
                hallx[((size_t)(s + 1) * NB + b2) * NH + c0 + col] = f2bf(hnew);
            }
            __syncthreads();
            if (t == 0) arrive(C2, F2, RB_BLOCKS, s);
        }
    }
}

// ---------------- in-place log_softmax per row of d_out ----------------
__global__ __launch_bounds__(256) void logsoftmax_kernel(float* __restrict__ out) {
    __shared__ float red[8];
    float* row = out + (size_t)blockIdx.x * NV;
    int t = threadIdx.x;
    float m = -1e30f;
    for (int i = t; i < NV; i += 256) m = fmaxf(m, row[i]);
    for (int o = 32; o >= 1; o >>= 1) m = fmaxf(m, __shfl_xor(m, o));
    if ((t & 63) == 0) red[t >> 6] = m;
    __syncthreads();
    m = fmaxf(fmaxf(red[0], red[1]), fmaxf(red[2], red[3]));
    float sum = 0.f;
    for (int i = t; i < NV; i += 256) sum += __expf(row[i] - m);
    for (int o = 32; o >= 1; o >>= 1) sum += __shfl_xor(sum, o);
    if ((t & 63) == 0) red[4 + (t >> 6)] = sum;
    __syncthreads();
    sum = (red[4] + red[5]) + (red[6] + red[7]);
    float lse = m + __logf(sum);
    for (int i = t; i < NV; i += 256) row[i] = row[i] - lse;
}

extern "C" void kernel_launch(void* const* d_in, const int* in_sizes, int n_in,
                              void* d_out, int out_size, void* d_ws, size_t ws_size,
                              hipStream_t stream) {
    const int*   label = (const int*)  d_in[0];
    const float* inith = (const float*)d_in[1];
    const float* enc   = (const float*)d_in[2];
    const float* emb   = (const float*)d_in[3];
    const float* attnW = (const float*)d_in[4];
    const float* attnB = (const float*)d_in[5];
    const float* combW = (const float*)d_in[6];
    const float* combB = (const float*)d_in[7];
    const float* Wih   = (const float*)d_in[8];
    const float* Whh   = (const float*)d_in[9];
    const float* bih   = (const float*)d_in[10];
    const float* bhh   = (const float*)d_in[11];
    const float* outW  = (const float*)d_in[12];
    const float* outB  = (const float*)d_in[13];
    char* ws = (char*)d_ws;

    // workspace carve (bytes) -- same footprint as round 1
    size_t BAR_OFF   = 0;                               // 512
    size_t OUTWT_OFF = 512;                             // bf16 [V][H]
    size_t WHHT_OFF  = OUTWT_OFF + (size_t)NV*NH*2;
    size_t WIHT_OFF  = WHHT_OFF + (size_t)K3H*NH*2;
    size_t CW1T_OFF  = WIHT_OFF + (size_t)K3H*NH*2;
    size_t CW2T_OFF  = CW1T_OFF + (size_t)NH*NH*2;
    size_t AW2T_OFF  = CW2T_OFF + (size_t)NH*NH*2;      // bf16 [48][1024] + aw1t after
    size_t AW1T_OFF  = AW2T_OFF + (size_t)NL*NH*2;
    size_t XE_OFF    = AW2T_OFF + (size_t)NL*NH*4;      // keep old region size
    size_t ENCB_OFF  = XE_OFF   + (size_t)NR*NE*2;
    size_t SIMXE_OFF = ENCB_OFF + (size_t)NR*NH*2;
    size_t GXE_OFF   = SIMXE_OFF+ (size_t)NR*NL*4;
    size_t P_OFF     = GXE_OFF  + (size_t)NR*NH*2;
    size_t HALL_OFF  = P_OFF    + (size_t)NR*NH*2;      // hallx: [49][B][H] bf16
    size_t WATT_OFF  = HALL_OFF + (size_t)(NS+1)*NB*NH*2;
    size_t GH_OFF    = WATT_OFF + (size_t)NB*NL*4;
    size_t GBF_OFF   = GH_OFF   + (size_t)NB*K3H*4;     // g_glob bf16 [B][H]

    int*   bar   = (int*)(ws + BAR_OFF);
    u16*   outWT = (u16*)(ws + OUTWT_OFF);
    u16*   whht  = (u16*)(ws + WHHT_OFF);
    u16*   wiht  = (u16*)(ws + WIHT_OFF);
    u16*   cw1t  = (u16*)(ws + CW1T_OFF);
    u16*   cw2t  = (u16*)(ws + CW2T_OFF);
    u16*   aw2t  = (u16*)(ws + AW2T_OFF);
    u16*   aw1t  = (u16*)(ws + AW1T_OFF);
    u16*   xe    = (u16*)(ws + XE_OFF);
    u16*   encb  = (u16*)(ws + ENCB_OFF);
    float* simxe = (float*)(ws + SIMXE_OFF);
    u16*   gxe   = (u16*)(ws + GXE_OFF);
    u16*   Pb    = (u16*)(ws + P_OFF);
    u16*   hallx = (u16*)(ws + HALL_OFF);
    u16*   gglob = (u16*)(ws + GBF_OFF);

    hipMemsetAsync(bar, 0, 512, stream);
    prep_inputs<<<2 * NR + NB, 256, 0, stream>>>(label, emb, enc, inith, xe, encb, hallx);

    transpose_cast<<<dim3(NV / 32, 32), 256, 0, stream>>>(outW, NH, NV, (char*)outWT, 1);
    transpose_cast<<<dim3(K3H / 32, 32), 256, 0, stream>>>(Whh, NH, K3H, (char*)whht, 1);
    transpose_cast<<<dim3(K3H / 32, 32), 256, 0, stream>>>(Wih, NH, K3H, (char*)wiht, 1);
    transpose_cast<<<dim3(NH / 32, 32), 256, 0, stream>>>(combW, NH, NH, (char*)cw1t, 1);
    transpose_cast<<<dim3(NH / 32, 32), 256, 0, stream>>>(combW + (size_t)NH * NH, NH, NH, (char*)cw2t, 1);
    transpose_cast<<<dim3(2, 32), 256, 0, stream>>>(attnW + (size_t)NH * NL, NH, NL, (char*)aw2t, 1);
    transpose_cast<<<dim3(2, 32), 256, 0, stream>>>(attnW, NH, NL, (char*)aw1t, 1);

    simxe2_kernel<<<NR, 384, 0, stream>>>(xe, aw1t, attnB, simxe);
    gemm_bf16<2><<<dim3(NR / 128, NH / 128), 256, 0, stream>>>(xe, cw2t, gxe, combB, NH);
    gemm_bf16<2><<<dim3(NR / 128, NH / 128), 256, 0, stream>>>(encb, cw1t, Pb, nullptr, NH);

    recurrence2<<<NBLK_R2, 512, 0, stream>>>(simxe, gxe, Pb, aw2t, whht, wiht,
                                             bih, bhh, gglob, hallx, bar);

    gemm_bf16<1><<<dim3(NR / 128, NV / 128), 256, 0, stream>>>(hallx + (size_t)NB * NH, outWT, d_out, outB, NV);
    logsoftmax_kernel<<<NR, 256, 0, stream>>>((float*)d_out);
}

// Round 3
// 1480.240 us; speedup vs baseline: 1.4404x; 1.0046x over previous
//
#include <hip/hip_runtime.h>

#define NB 32
#define NS 48
#define NL 48
#define NH 1024
#define NE 1024
#define NV 32000
#define NR (NS*NB)      // 1536
#define K3H 3072
#define RA_BLOCKS 64
#define RB_BLOCKS 128
#define NBLK_R2 (RA_BLOCKS + RB_BLOCKS)

typedef unsigned short u16;
typedef __bf16 bf16x8 __attribute__((ext_vector_type(8)));
typedef unsigned short ushort8 __attribute__((ext_vector_type(8)));
typedef float f32x4 __attribute__((ext_vector_type(4)));

__device__ __forceinline__ float bf2f(u16 x) {
    union { unsigned u; float f; } c; c.u = ((unsigned)x) << 16; return c.f;
}
__device__ __forceinline__ u16 f2bf(float f) {
    union { float f; unsigned u; } c; c.f = f;
    unsigned r = (c.u + 0x7FFFu + ((c.u >> 16) & 1u)) >> 16;
    return (u16)r;
}
__device__ __forceinline__ f32x4 mfma16(bf16x8 a, bf16x8 b, f32x4 c) {
    return __builtin_amdgcn_mfma_f32_16x16x32_bf16(a, b, c, 0, 0, 0);
}
__device__ __forceinline__ void gld_lds16(const void* g, void* l) {
    __builtin_amdgcn_global_load_lds((const __attribute__((address_space(1))) void*)g,
                                     (__attribute__((address_space(3))) void*)l, 16, 0, 0);
}

// ---------------- transpose + cast: dst[n][k] = src[k][n] ----------------
__global__ __launch_bounds__(256) void transpose_cast(const float* __restrict__ src, int K, int N,
                                                      char* __restrict__ dst, int bf16out) {
    __shared__ float tile[32][33];
    int k0 = blockIdx.y * 32, n0 = blockIdx.x * 32;
    int tx = threadIdx.x & 31, ty = threadIdx.x >> 5;
    for (int i = 0; i < 4; ++i) {
        int n = n0 + tx;
        float v = (n < N) ? src[(size_t)(k0 + ty + i*8) * N + n] : 0.f;
        tile[ty + i*8][tx] = v;
    }
    __syncthreads();
    for (int i = 0; i < 4; ++i) {
        int n = n0 + ty + i*8;
        int k = k0 + tx;
        if (n < N) {
            float v = tile[tx][ty + i*8];
            if (bf16out) ((u16*)dst)[(size_t)n * K + k] = f2bf(v);
            else         ((float*)dst)[(size_t)n * K + k] = v;
        }
    }
}

// ---------------- prep: xe=relu(emb[label]) -> bf16; enc -> bf16; init_h -> hallx[0] ----------------
__global__ __launch_bounds__(256) void prep_inputs(const int* __restrict__ label, const float* __restrict__ emb,
                                                   const float* __restrict__ enc, const float* __restrict__ inith,
                                                   u16* __restrict__ xe, u16* __restrict__ encb, u16* __restrict__ hallx) {
    int blk = blockIdx.x, t = threadIdx.x;
    if (blk < NR) {
        int s = blk >> 5, b = blk & 31;
        int lab = label[b * NS + s];
        const float* src = emb + (size_t)lab * NE;
        u16* dst = xe + (size_t)blk * NE;
        for (int i = t; i < NE; i += 256) { float v = src[i]; dst[i] = f2bf(v > 0.f ? v : 0.f); }
    } else if (blk < 2 * NR) {
        int r = blk - NR;
        const float* src = enc + (size_t)r * NH;
        u16* dst = encb + (size_t)r * NH;
        for (int i = t; i < NH; i += 256) dst[i] = f2bf(src[i]);
    } else {
        int b = blk - 2 * NR;
        const float* src = inith + (size_t)b * NH;
        u16* dst = hallx + (size_t)b * NH;   // slot 0 = h_{-1}
        for (int i = t; i < NH; i += 256) dst[i] = f2bf(src[i]);
    }
}

// ---------------- simxe[r][l] = xe[r,:] @ attn_W1^T[l,:] + attn_b[l] ----------------
__global__ __launch_bounds__(384) void simxe2_kernel(const u16* __restrict__ xe, const u16* __restrict__ aw1t,
                                                     const float* __restrict__ attnB, float* __restrict__ simxe) {
    int r = blockIdx.x, t = threadIdx.x;
    int l = t >> 3, part = t & 7;
    const u16* x = xe + (size_t)r * 1024 + part * 128;
    const u16* ww = aw1t + (size_t)l * 1024 + part * 128;
    float acc = 0.f;
#pragma unroll
    for (int k = 0; k < 128; k += 8) {
        ushort8 xv = *reinterpret_cast<const ushort8*>(x + k);
        ushort8 wv = *reinterpret_cast<const ushort8*>(ww + k);
#pragma unroll
        for (int u = 0; u < 8; ++u) acc += bf2f(xv[u]) * bf2f(wv[u]);
    }
    acc += __shfl_xor(acc, 1);
    acc += __shfl_xor(acc, 2);
    acc += __shfl_xor(acc, 4);
    if (part == 0) simxe[(size_t)r * NL + l] = acc + attnB[l];
}

// ---------------- bf16 MFMA GEMM, 128x128 tile, BK=64, K=1024 fixed ----------------
// MODE 0: f32 C[m*N+n]; MODE 1: f32 decoder-permuted; MODE 2: bf16 C[m*N+n]; MODE 3: bf16 decoder-permuted
template<int MODE>
__global__ __launch_bounds__(256) void gemm_bf16(const u16* __restrict__ A, const u16* __restrict__ Bt,
                                                 void* __restrict__ Cout, const float* __restrict__ bias, int N) {
    __shared__ u16 ldsA[128 * 64];
    __shared__ u16 ldsB[128 * 64];
    const int t = threadIdx.x;
    const int lane = t & 63, w = t >> 6;
    const int wm = w >> 1, wn = w & 1;
    const int m0 = blockIdx.x * 128, n0 = blockIdx.y * 128;
    f32x4 acc[4][4] = {};
    for (int kt = 0; kt < 16; ++kt) {
        const int k0 = kt * 64;
#pragma unroll
        for (int i = 0; i < 4; ++i) {
            int chunk = i * 256 + t;
            int row = chunk >> 3, slot = chunk & 7;
            int srck = ((slot ^ (row & 7)) * 8);
            const u16* ga = A  + (size_t)(m0 + row) * 1024 + k0 + srck;
            const u16* gb = Bt + (size_t)(n0 + row) * 1024 + k0 + srck;
            u16* la = ldsA + (size_t)(i * 256 + w * 64) * 8;
            u16* lb = ldsB + (size_t)(i * 256 + w * 64) * 8;
            gld_lds16(ga, la);
            gld_lds16(gb, lb);
        }
        asm volatile("s_waitcnt vmcnt(0)" ::: "memory");
        __syncthreads();
#pragma unroll
        for (int kk = 0; kk < 2; ++kk) {
            bf16x8 a[4], b[4];
#pragma unroll
            for (int f = 0; f < 4; ++f) {
                int rowA = wm * 64 + f * 16 + (lane & 15);
                int slotA = (kk * 4 + (lane >> 4)) ^ (rowA & 7);
                a[f] = *reinterpret_cast<const bf16x8*>(ldsA + rowA * 64 + slotA * 8);
                int rowB = wn * 64 + f * 16 + (lane & 15);
                int slotB = (kk * 4 + (lane >> 4)) ^ (rowB & 7);
                b[f] = *reinterpret_cast<const bf16x8*>(ldsB + rowB * 64 + slotB * 8);
            }
#pragma unroll
            for (int fm = 0; fm < 4; ++fm)
#pragma unroll
                for (int fn = 0; fn < 4; ++fn)
                    acc[fm][fn] = mfma16(a[fm], b[fn], acc[fm][fn]);
        }
        __syncthreads();
    }
#pragma unroll
    for (int fm = 0; fm < 4; ++fm) {
#pragma unroll
        for (int fn = 0; fn < 4; ++fn) {
#pragma unroll
            for (int rr = 0; rr < 4; ++rr) {
                int m = m0 + wm * 64 + fm * 16 + (lane >> 4) * 4 + rr;
                int n = n0 + wn * 64 + fn * 16 + (lane & 15);
                float v = acc[fm][fn][rr];
                if (bias) v += bias[n];
                if (MODE == 0)      ((float*)Cout)[(size_t)m * N + n] = v;
                else if (MODE == 2) ((u16*)Cout)[(size_t)m * N + n] = f2bf(v);
                else if (MODE == 1)
                    ((float*)Cout)[((size_t)(m & 31) * NS + (m >> 5)) * NV + n] = v;
                else
                    ((u16*)Cout)[((size_t)(m & 31) * NS + (m >> 5)) * NV + n] = f2bf(v);
            }
        }
    }
}

// ---------------- sync primitives: grouped arrive + master poll ----------------
__device__ __forceinline__ void wait_master(int* m, int tgt) {
    int guard = 0;
    while (__hip_atomic_load(m, __ATOMIC_RELAXED, __HIP_MEMORY_SCOPE_AGENT) < tgt) {
        __builtin_amdgcn_s_sleep(1);
        if (++guard > (1 << 25)) break;   // safety valve: wrong answer, not hang
    }
    __builtin_amdgcn_fence(__ATOMIC_ACQUIRE, "agent");
}
// grp counter: cumulative across steps, 8 members each. RELEASE flushes this block's data.
__device__ __forceinline__ void arrive_grp(int* grp, int* master) {
    int prev = __hip_atomic_fetch_add(grp, 1, __ATOMIC_RELEASE, __HIP_MEMORY_SCOPE_AGENT);
    if ((prev & 7) == 7)
        __hip_atomic_fetch_add(master, 1, __ATOMIC_RELAXED, __HIP_MEMORY_SCOPE_AGENT);
}

// ---------------- persistent recurrence, role-split, grouped-flag sync ----------------
// masterA advances 8/step (g ready); masterB advances 16/step (h ready).
__global__ __launch_bounds__(512) void recurrence3(
    const float* __restrict__ simxe, const u16* __restrict__ gxe,
    const u16* __restrict__ P, const u16* __restrict__ aw2t,
    const u16* __restrict__ whht, const u16* __restrict__ wiht,
    const float* __restrict__ b_ih, const float* __restrict__ b_hh,
    u16* __restrict__ g_glob, u16* __restrict__ hallx, int* __restrict__ bar)
{
    __shared__ __align__(16) char smem[154624];
    int* masterA = bar + 768;
    int* masterB = bar + 800;
    const int blk = blockIdx.x, t = threadIdx.x;
    const int lane = t & 63, w = t >> 6;
    const int r16 = lane & 15, kg = lane >> 4;

    if (blk < RA_BLOCKS) {
        // =========== ROLE A ===========
        int* myGrp = bar + 32 * (blk >> 3);
        const int b = blk >> 1, half = blk & 1;
        u16*   W2T  = (u16*)smem;                    // [48][1032] bf16
        u16*   Pl   = (u16*)(smem + 99072);          // [48][512] bf16
        float* siml = (float*)(smem + 148224);       // [32][48] f32
        float* wl   = (float*)(smem + 154368);       // [48] f32
        for (int idx = t; idx < 48 * 1024; idx += 512) {
            int l = idx >> 10, k = idx & 1023;
            W2T[l * 1032 + k] = aw2t[idx];
        }
        for (int idx = t; idx < 48 * 512; idx += 512) {
            int l = idx >> 9, j = idx & 511;
            Pl[idx] = P[((size_t)(b * 48 + l)) * NH + half * 512 + j];
        }
        __syncthreads();

        for (int s = 0; s < NS; ++s) {
            if (t == 0) wait_master(masterB, 16 * s);
            __syncthreads();
            const u16* hprev = hallx + (size_t)s * (NB * NH);
            // issue h-independent loads early
            float gxev = bf2f(gxe[((size_t)(s * 32 + b)) * NH + half * 512 + t]);
            // --- sim = h @ W2 (+ simxe via acc init): 6 waves
            if (w < 6) {
                const int mt = w & 1, nt = w >> 1;
                const int m0 = mt * 16, n0 = nt * 16;
                f32x4 acc0; f32x4 acc1 = {};
                const float* sxe = simxe + (size_t)(s * 32) * NL;
#pragma unroll
                for (int rr = 0; rr < 4; ++rr)
                    acc0[rr] = sxe[(m0 + kg * 4 + rr) * NL + n0 + r16];
                const u16* aP = hprev + (size_t)(m0 + r16) * NH + kg * 8;
                const u16* bP = W2T + (n0 + r16) * 1032 + kg * 8;
#pragma unroll 4
                for (int k = 0; k < 1024; k += 64) {
                    acc0 = mfma16(*reinterpret_cast<const bf16x8*>(aP + k),
                                  *reinterpret_cast<const bf16x8*>(bP + k), acc0);
                    acc1 = mfma16(*reinterpret_cast<const bf16x8*>(aP + k + 32),
                                  *reinterpret_cast<const bf16x8*>(bP + k + 32), acc1);
                }
#pragma unroll
                for (int rr = 0; rr < 4; ++rr)
                    siml[(m0 + kg * 4 + rr) * NL + n0 + r16] = acc0[rr] + acc1[rr];
            }
            __syncthreads();
            // --- softmax over batch (col-wise), keep only row b
            if (t < NL) {
                float m = -1e30f;
                for (int b2 = 0; b2 < NB; ++b2) m = fmaxf(m, siml[b2 * NL + t]);
                float den = 0.f;
                for (int b2 = 0; b2 < NB; ++b2) den += __expf(siml[b2 * NL + t] - m);
                wl[t] = __expf(siml[b * NL + t] - m) / den;
            }
            __syncthreads();
            // --- g[b][half*512 + t] = relu(gxe + sum_l wl[l]*P[l][t])
            {
                float acc = gxev;
#pragma unroll
                for (int l = 0; l < 48; ++l) acc += wl[l] * bf2f(Pl[l * 512 + t]);
                g_glob[b * NH + half * 512 + t] = f2bf(fmaxf(acc, 0.f));
            }
            __syncthreads();
            if (t == 0) arrive_grp(myGrp, masterA);
        }
    } else {
        // =========== ROLE B ===========
        int* myGrp = bar + 256 + 32 * ((blk - RA_BLOCKS) >> 3);
        const int c0 = (blk - RA_BLOCKS) * 8;
        u16*   Whh = (u16*)smem;                     // [32][1032] bf16 (rows 24..31 zero)
        u16*   Wih = (u16*)(smem + 66048);           // [32][1032] bf16
        float* ghs = (float*)(smem + 132096);        // [2][32][32] f32
        float* gxs = (float*)(smem + 140288);        // [2][32][32] f32
        for (int idx = t; idx < 32 * 1024; idx += 512) {
            int pr = idx >> 10, k = idx & 1023;
            u16 vh = 0, vi = 0;
            if (pr < 24) {
                size_t srow = (size_t)((pr >> 3) * 1024 + c0 + (pr & 7));
                vh = whht[srow * NH + k];
                vi = wiht[srow * NH + k];
            }
            Whh[pr * 1032 + k] = vh;
            Wih[pr * 1032 + k] = vi;
        }
        // preload gate biases to registers (avoid post-inv MALL refetch each step)
        const int gb2 = t >> 3, gcol = t & 7;
        const float bxr = b_ih[c0 + gcol],        bxz = b_ih[1024 + c0 + gcol], bxn = b_ih[2048 + c0 + gcol];
        const float bhr = b_hh[c0 + gcol],        bhz = b_hh[1024 + c0 + gcol], bhn = b_hh[2048 + c0 + gcol];
        __syncthreads();
        const int mt = (w >> 1) & 1, nt = w & 1, kh = w >> 2;
        const int m0 = mt * 16;

        for (int s = 0; s < NS; ++s) {
            if (t == 0) wait_master(masterB, 16 * s);
            __syncthreads();
            const u16* hprev = hallx + (size_t)s * (NB * NH);
            // --- gh = h @ W_hh slice (8 waves: 2m x 2n x 2k-halves)
            {
                f32x4 acc0 = {}, acc1 = {};
                const u16* aP = hprev + (size_t)(m0 + r16) * NH + kh * 512 + kg * 8;
                const u16* bP = Whh + (nt * 16 + r16) * 1032 + kh * 512 + kg * 8;
#pragma unroll 4
                for (int k = 0; k < 512; k += 64) {
                    acc0 = mfma16(*reinterpret_cast<const bf16x8*>(aP + k),
                                  *reinterpret_cast<const bf16x8*>(bP + k), acc0);
                    acc1 = mfma16(*reinterpret_cast<const bf16x8*>(aP + k + 32),
                                  *reinterpret_cast<const bf16x8*>(bP + k + 32), acc1);
                }
#pragma unroll
                for (int rr = 0; rr < 4; ++rr)
                    ghs[kh * 1024 + (m0 + kg * 4 + rr) * 32 + nt * 16 + r16] = acc0[rr] + acc1[rr];
            }
            if (t == 0) wait_master(masterA, 8 * (s + 1));
            __syncthreads();
            // --- gx = g @ W_ih slice
            {
                f32x4 acc0 = {}, acc1 = {};
                const u16* aP = g_glob + (size_t)(m0 + r16) * NH + kh * 512 + kg * 8;
                const u16* bP = Wih + (nt * 16 + r16) * 1032 + kh * 512 + kg * 8;
#pragma unroll 4
                for (int k = 0; k < 512; k += 64) {
                    acc0 = mfma16(*reinterpret_cast<const bf16x8*>(aP + k),
                                  *reinterpret_cast<const bf16x8*>(bP + k), acc0);
                    acc1 = mfma16(*reinterpret_cast<const bf16x8*>(aP + k + 32),
                                  *reinterpret_cast<const bf16x8*>(bP + k + 32), acc1);
                }
#pragma unroll
                for (int rr = 0; rr < 4; ++rr)
                    gxs[kh * 1024 + (m0 + kg * 4 + rr) * 32 + nt * 16 + r16] = acc0[rr] + acc1[rr];
            }
            __syncthreads();
            // --- gates + h_new for (32 batches x 8 cols)
            if (t < 256) {
                float gxr = gxs[gb2 * 32 + gcol]      + gxs[1024 + gb2 * 32 + gcol]      + bxr;
                float gxz = gxs[gb2 * 32 + 8 + gcol]  + gxs[1024 + gb2 * 32 + 8 + gcol]  + bxz;
                float gxn = gxs[gb2 * 32 + 16 + gcol] + gxs[1024 + gb2 * 32 + 16 + gcol] + bxn;
                float ghr = ghs[gb2 * 32 + gcol]      + ghs[1024 + gb2 * 32 + gcol]      + bhr;
                float ghz = ghs[gb2 * 32 + 8 + gcol]  + ghs[1024 + gb2 * 32 + 8 + gcol]  + bhz;
                float ghn = ghs[gb2 * 32 + 16 + gcol] + ghs[1024 + gb2 * 32 + 16 + gcol] + bhn;
                float rg = 1.f / (1.f + __expf(-(gxr + ghr)));
                float zg = 1.f / (1.f + __expf(-(gxz + ghz)));
                float ng = tanhf(gxn + rg * ghn);
                float hold = bf2f(hprev[gb2 * NH + c0 + gcol]);
                float hnew = (1.f - zg) * ng + zg * hold;
                hallx[((size_t)(s + 1) * NB + gb2) * NH + c0 + gcol] = f2bf(hnew);
            }
            __syncthreads();
            if (t == 0) arrive_grp(myGrp, masterB);
        }
    }
}

// ---------------- log_softmax: f32 in-place variant ----------------
__global__ __launch_bounds__(256) void logsoftmax_kernel(float* __restrict__ out) {
    __shared__ float red[8];
    float* row = out + (size_t)blockIdx.x * NV;
    int t = threadIdx.x;
    float m = -1e30f;
    for (int i = t; i < NV; i += 256) m = fmaxf(m, row[i]);
    for (int o = 32; o >= 1; o >>= 1) m = fmaxf(m, __shfl_xor(m, o));
    if ((t & 63) == 0) red[t >> 6] = m;
    __syncthreads();
    m = fmaxf(fmaxf(red[0], red[1]), fmaxf(red[2], red[3]));
    float sum = 0.f;
    for (int i = t; i < NV; i += 256) sum += __expf(row[i] - m);
    for (int o = 32; o >= 1; o >>= 1) sum += __shfl_xor(sum, o);
    if ((t & 63) == 0) red[4 + (t >> 6)] = sum;
    __syncthreads();
    sum = (red[4] + red[5]) + (red[6] + red[7]);
    float lse = m + __logf(sum);
    for (int i = t; i < NV; i += 256) row[i] = row[i] - lse;
}

// ---------------- log_softmax: bf16-staged variant (reads ws logits, writes f32 out) ----------------
__global__ __launch_bounds__(256) void logsoftmax_bf16(const u16* __restrict__ lg, float* __restrict__ out) {
    __shared__ __align__(16) u16 rowb[NV];   // 64000 B
    __shared__ float red[8];
    const u16* src = lg + (size_t)blockIdx.x * NV;
    float* dst = out + (size_t)blockIdx.x * NV;
    int t = threadIdx.x;
    for (int i = t; i < NV / 8; i += 256)
        ((ushort8*)rowb)[i] = ((const ushort8*)src)[i];
    __syncthreads();
    float m = -1e30f;
    for (int i = t; i < NV; i += 256) m = fmaxf(m, bf2f(rowb[i]));
    for (int o = 32; o >= 1; o >>= 1) m = fmaxf(m, __shfl_xor(m, o));
    if ((t & 63) == 0) red[t >> 6] = m;
    __syncthreads();
    m = fmaxf(fmaxf(red[0], red[1]), fmaxf(red[2], red[3]));
    float sum = 0.f;
    for (int i = t; i < NV; i += 256) sum += __expf(bf2f(rowb[i]) - m);
    for (int o = 32; o >= 1; o >>= 1) sum += __shfl_xor(sum, o);
    if ((t & 63) == 0) red[4 + (t >> 6)] = sum;
    __syncthreads();
    sum = (red[4] + red[5]) + (red[6] + red[7]);
    float lse = m + __logf(sum);
    for (int i = t; i < NV; i += 256) dst[i] = bf2f(rowb[i]) - lse;
}

extern "C" void kernel_launch(void* const* d_in, const int* in_sizes, int n_in,
                              void* d_out, int out_size, void* d_ws, size_t ws_size,
                              hipStream_t stream) {
    const int*   label = (const int*)  d_in[0];
    const float* inith = (const float*)d_in[1];
    const float* enc   = (const float*)d_in[2];
    const float* emb   = (const float*)d_in[3];
    const float* attnW = (const float*)d_in[4];
    const float* attnB = (const float*)d_in[5];
    const float* combW = (const float*)d_in[6];
    const float* combB = (const float*)d_in[7];
    const float* Wih   = (const float*)d_in[8];
    const float* Whh   = (const float*)d_in[9];
    const float* bih   = (const float*)d_in[10];
    const float* bhh   = (const float*)d_in[11];
    const float* outW  = (const float*)d_in[12];
    const float* outB  = (const float*)d_in[13];
    char* ws = (char*)d_ws;

    // workspace carve (bytes)
    size_t BAR_OFF    = 0;                                // 4096
    size_t OUTWT_OFF  = 4096;
    size_t WHHT_OFF   = OUTWT_OFF + (size_t)NV*NH*2;
    size_t WIHT_OFF   = WHHT_OFF + (size_t)K3H*NH*2;
    size_t CW1T_OFF   = WIHT_OFF + (size_t)K3H*NH*2;
    size_t CW2T_OFF   = CW1T_OFF + (size_t)NH*NH*2;
    size_t AW2T_OFF   = CW2T_OFF + (size_t)NH*NH*2;
    size_t AW1T_OFF   = AW2T_OFF + (size_t)NL*NH*2;
    size_t XE_OFF     = AW2T_OFF + (size_t)NL*NH*4;
    size_t ENCB_OFF   = XE_OFF   + (size_t)NR*NE*2;
    size_t SIMXE_OFF  = ENCB_OFF + (size_t)NR*NH*2;
    size_t GXE_OFF    = SIMXE_OFF+ (size_t)NR*NL*4;
    size_t P_OFF      = GXE_OFF  + (size_t)NR*NH*2;
    size_t HALL_OFF   = P_OFF    + (size_t)NR*NH*2;       // hallx [49][B][H] bf16
    size_t GGLOB_OFF  = HALL_OFF + (size_t)(NS+1)*NB*NH*2;
    size_t LOGIT_OFF  = GGLOB_OFF+ (size_t)NB*NH*2;       // bf16 logits [NR][NV]
    size_t TOTAL_NEED = LOGIT_OFF+ (size_t)NR*NV*2;

    int*   bar   = (int*)(ws + BAR_OFF);
    u16*   outWT = (u16*)(ws + OUTWT_OFF);
    u16*   whht  = (u16*)(ws + WHHT_OFF);
    u16*   wiht  = (u16*)(ws + WIHT_OFF);
    u16*   cw1t  = (u16*)(ws + CW1T_OFF);
    u16*   cw2t  = (u16*)(ws + CW2T_OFF);
    u16*   aw2t  = (u16*)(ws + AW2T_OFF);
    u16*   aw1t  = (u16*)(ws + AW1T_OFF);
    u16*   xe    = (u16*)(ws + XE_OFF);
    u16*   encb  = (u16*)(ws + ENCB_OFF);
    float* simxe = (float*)(ws + SIMXE_OFF);
    u16*   gxe   = (u16*)(ws + GXE_OFF);
    u16*   Pb    = (u16*)(ws + P_OFF);
    u16*   hallx = (u16*)(ws + HALL_OFF);
    u16*   gglob = (u16*)(ws + GGLOB_OFF);
    u16*   logit = (u16*)(ws + LOGIT_OFF);

    hipMemsetAsync(bar, 0, 4096, stream);
    prep_inputs<<<2 * NR + NB, 256, 0, stream>>>(label, emb, enc, inith, xe, encb, hallx);

    transpose_cast<<<dim3(NV / 32, 32), 256, 0, stream>>>(outW, NH, NV, (char*)outWT, 1);
    transpose_cast<<<dim3(K3H / 32, 32), 256, 0, stream>>>(Whh, NH, K3H, (char*)whht, 1);
    transpose_cast<<<dim3(K3H / 32, 32), 256, 0, stream>>>(Wih, NH, K3H, (char*)wiht, 1);
    transpose_cast<<<dim3(NH / 32, 32), 256, 0, stream>>>(combW, NH, NH, (char*)cw1t, 1);
    transpose_cast<<<dim3(NH / 32, 32), 256, 0, stream>>>(combW + (size_t)NH * NH, NH, NH, (char*)cw2t, 1);
    transpose_cast<<<dim3(2, 32), 256, 0, stream>>>(attnW + (size_t)NH * NL, NH, NL, (char*)aw2t, 1);
    transpose_cast<<<dim3(2, 32), 256, 0, stream>>>(attnW, NH, NL, (char*)aw1t, 1);

    simxe2_kernel<<<NR, 384, 0, stream>>>(xe, aw1t, attnB, simxe);
    gemm_bf16<2><<<dim3(NR / 128, NH / 128), 256, 0, stream>>>(xe, cw2t, gxe, combB, NH);
    gemm_bf16<2><<<dim3(NR / 128, NH / 128), 256, 0, stream>>>(encb, cw1t, Pb, nullptr, NH);

    recurrence3<<<NBLK_R2, 512, 0, stream>>>(simxe, gxe, Pb, aw2t, whht, wiht,
                                             bih, bhh, gglob, hallx, bar);

    if (ws_size >= TOTAL_NEED) {
        gemm_bf16<3><<<dim3(NR / 128, NV / 128), 256, 0, stream>>>(hallx + (size_t)NB * NH, outWT, logit, outB, NV);
        logsoftmax_bf16<<<NR, 256, 0, stream>>>(logit, (float*)d_out);
    } else {
        gemm_bf16<1><<<dim3(NR / 128, NV / 128), 256, 0, stream>>>(hallx + (size_t)NB * NH, outWT, d_out, outB, NV);
        logsoftmax_kernel<<<NR, 256, 0, stream>>>((float*)d_out);
    }
}

// Round 4
// 1238.388 us; speedup vs baseline: 1.7217x; 1.1953x over previous
//
#include <hip/hip_runtime.h>

#define NB 32
#define NS 48
#define NL 48
#define NH 1024
#define NE 1024
#define NV 32000
#define NR (NS*NB)      // 1536
#define K3H 3072
#define RA_BLOCKS 64
#define RB_BLOCKS 128
#define NBLK_R2 (RA_BLOCKS + RB_BLOCKS)

typedef unsigned short u16;
typedef __bf16 bf16x8 __attribute__((ext_vector_type(8)));
typedef unsigned short ushort8 __attribute__((ext_vector_type(8)));
typedef float f32x4 __attribute__((ext_vector_type(4)));
typedef unsigned int uint4v __attribute__((ext_vector_type(4)));

__device__ __forceinline__ float bf2f(u16 x) {
    union { unsigned u; float f; } c; c.u = ((unsigned)x) << 16; return c.f;
}
__device__ __forceinline__ u16 f2bf(float f) {
    union { float f; unsigned u; } c; c.f = f;
    unsigned r = (c.u + 0x7FFFu + ((c.u >> 16) & 1u)) >> 16;
    return (u16)r;
}
__device__ __forceinline__ f32x4 mfma16(bf16x8 a, bf16x8 b, f32x4 c) {
    return __builtin_amdgcn_mfma_f32_16x16x32_bf16(a, b, c, 0, 0, 0);
}
__device__ __forceinline__ void gld_lds16(const void* g, void* l) {
    __builtin_amdgcn_global_load_lds((const __attribute__((address_space(1))) void*)g,
                                     (__attribute__((address_space(3))) void*)l, 16, 0, 0);
}

// ---- coherent (MALL-serialized, cache-bypassing) access primitives ----
// 16 batched 16B loads from base P (byte offsets 0..960), results must pass TIE16 before use.
#define LOAD16(A, P) \
  asm volatile("global_load_dwordx4 %0, %1, off sc0 sc1"            : "=v"(A[0])  : "v"(P)); \
  asm volatile("global_load_dwordx4 %0, %1, off offset:64 sc0 sc1"  : "=v"(A[1])  : "v"(P)); \
  asm volatile("global_load_dwordx4 %0, %1, off offset:128 sc0 sc1" : "=v"(A[2])  : "v"(P)); \
  asm volatile("global_load_dwordx4 %0, %1, off offset:192 sc0 sc1" : "=v"(A[3])  : "v"(P)); \
  asm volatile("global_load_dwordx4 %0, %1, off offset:256 sc0 sc1" : "=v"(A[4])  : "v"(P)); \
  asm volatile("global_load_dwordx4 %0, %1, off offset:320 sc0 sc1" : "=v"(A[5])  : "v"(P)); \
  asm volatile("global_load_dwordx4 %0, %1, off offset:384 sc0 sc1" : "=v"(A[6])  : "v"(P)); \
  asm volatile("global_load_dwordx4 %0, %1, off offset:448 sc0 sc1" : "=v"(A[7])  : "v"(P)); \
  asm volatile("global_load_dwordx4 %0, %1, off offset:512 sc0 sc1" : "=v"(A[8])  : "v"(P)); \
  asm volatile("global_load_dwordx4 %0, %1, off offset:576 sc0 sc1" : "=v"(A[9])  : "v"(P)); \
  asm volatile("global_load_dwordx4 %0, %1, off offset:640 sc0 sc1" : "=v"(A[10]) : "v"(P)); \
  asm volatile("global_load_dwordx4 %0, %1, off offset:704 sc0 sc1" : "=v"(A[11]) : "v"(P)); \
  asm volatile("global_load_dwordx4 %0, %1, off offset:768 sc0 sc1" : "=v"(A[12]) : "v"(P)); \
  asm volatile("global_load_dwordx4 %0, %1, off offset:832 sc0 sc1" : "=v"(A[13]) : "v"(P)); \
  asm volatile("global_load_dwordx4 %0, %1, off offset:896 sc0 sc1" : "=v"(A[14]) : "v"(P)); \
  asm volatile("global_load_dwordx4 %0, %1, off offset:960 sc0 sc1" : "=v"(A[15]) : "v"(P));

#define TIE16(A) asm volatile("s_waitcnt vmcnt(0)" : \
  "+v"(A[0]),"+v"(A[1]),"+v"(A[2]),"+v"(A[3]),"+v"(A[4]),"+v"(A[5]),"+v"(A[6]),"+v"(A[7]), \
  "+v"(A[8]),"+v"(A[9]),"+v"(A[10]),"+v"(A[11]),"+v"(A[12]),"+v"(A[13]),"+v"(A[14]),"+v"(A[15]))

#define TIE17(A, X) asm volatile("s_waitcnt vmcnt(0)" : \
  "+v"(A[0]),"+v"(A[1]),"+v"(A[2]),"+v"(A[3]),"+v"(A[4]),"+v"(A[5]),"+v"(A[6]),"+v"(A[7]), \
  "+v"(A[8]),"+v"(A[9]),"+v"(A[10]),"+v"(A[11]),"+v"(A[12]),"+v"(A[13]),"+v"(A[14]),"+v"(A[15]),"+v"(X))

__device__ __forceinline__ void st16_coh(void* p, uint4v v) {
    asm volatile("global_store_dwordx4 %0, %1, off sc0 sc1" :: "v"(p), "v"(v) : "memory");
}
// producer: all my stores visible at MALL, then bump the line counter (device scope via sc1)
__device__ __forceinline__ void bumpline(int* p) {
    int one = 1;
    asm volatile("s_waitcnt vmcnt(0)\n\tglobal_atomic_add %0, %1, off sc1"
                 :: "v"(p), "v"(one) : "memory");
}
// waiter: sum 8 counter lines (256B apart) until >= tgt
__device__ __forceinline__ void waitsum(const int* base, int tgt) {
    if (tgt <= 0) return;
    int guard = 0;
    for (;;) {
        int v0,v1,v2,v3,v4,v5,v6,v7;
        asm volatile(
            "global_load_dword %0, %8, off sc0 sc1\n\t"
            "global_load_dword %1, %8, off offset:256 sc0 sc1\n\t"
            "global_load_dword %2, %8, off offset:512 sc0 sc1\n\t"
            "global_load_dword %3, %8, off offset:768 sc0 sc1\n\t"
            "global_load_dword %4, %8, off offset:1024 sc0 sc1\n\t"
            "global_load_dword %5, %8, off offset:1280 sc0 sc1\n\t"
            "global_load_dword %6, %8, off offset:1536 sc0 sc1\n\t"
            "global_load_dword %7, %8, off offset:1792 sc0 sc1\n\t"
            "s_waitcnt vmcnt(0)"
            : "=v"(v0),"=v"(v1),"=v"(v2),"=v"(v3),"=v"(v4),"=v"(v5),"=v"(v6),"=v"(v7)
            : "v"(base) : "memory");
        if (((v0+v1)+(v2+v3))+((v4+v5)+(v6+v7)) >= tgt) return;
        __builtin_amdgcn_s_sleep(1);
        if (++guard > (1 << 18)) return;   // safety valve: wrong answer, not hang
    }
}

// ---------------- transpose + cast: dst[n][k] = src[k][n] ----------------
__global__ __launch_bounds__(256) void transpose_cast(const float* __restrict__ src, int K, int N,
                                                      char* __restrict__ dst, int bf16out) {
    __shared__ float tile[32][33];
    int k0 = blockIdx.y * 32, n0 = blockIdx.x * 32;
    int tx = threadIdx.x & 31, ty = threadIdx.x >> 5;
    for (int i = 0; i < 4; ++i) {
        int n = n0 + tx;
        float v = (n < N) ? src[(size_t)(k0 + ty + i*8) * N + n] : 0.f;
        tile[ty + i*8][tx] = v;
    }
    __syncthreads();
    for (int i = 0; i < 4; ++i) {
        int n = n0 + ty + i*8;
        int k = k0 + tx;
        if (n < N) {
            float v = tile[tx][ty + i*8];
            if (bf16out) ((u16*)dst)[(size_t)n * K + k] = f2bf(v);
            else         ((float*)dst)[(size_t)n * K + k] = v;
        }
    }
}

// ---------------- prep ----------------
__global__ __launch_bounds__(256) void prep_inputs(const int* __restrict__ label, const float* __restrict__ emb,
                                                   const float* __restrict__ enc, const float* __restrict__ inith,
                                                   u16* __restrict__ xe, u16* __restrict__ encb, u16* __restrict__ hallx) {
    int blk = blockIdx.x, t = threadIdx.x;
    if (blk < NR) {
        int s = blk >> 5, b = blk & 31;
        int lab = label[b * NS + s];
        const float* src = emb + (size_t)lab * NE;
        u16* dst = xe + (size_t)blk * NE;
        for (int i = t; i < NE; i += 256) { float v = src[i]; dst[i] = f2bf(v > 0.f ? v : 0.f); }
    } else if (blk < 2 * NR) {
        int r = blk - NR;
        const float* src = enc + (size_t)r * NH;
        u16* dst = encb + (size_t)r * NH;
        for (int i = t; i < NH; i += 256) dst[i] = f2bf(src[i]);
    } else {
        int b = blk - 2 * NR;
        const float* src = inith + (size_t)b * NH;
        u16* dst = hallx + (size_t)b * NH;   // slot 0 = h_{-1}
        for (int i = t; i < NH; i += 256) dst[i] = f2bf(src[i]);
    }
}

// ---------------- simxe ----------------
__global__ __launch_bounds__(384) void simxe2_kernel(const u16* __restrict__ xe, const u16* __restrict__ aw1t,
                                                     const float* __restrict__ attnB, float* __restrict__ simxe) {
    int r = blockIdx.x, t = threadIdx.x;
    int l = t >> 3, part = t & 7;
    const u16* x = xe + (size_t)r * 1024 + part * 128;
    const u16* ww = aw1t + (size_t)l * 1024 + part * 128;
    float acc = 0.f;
#pragma unroll
    for (int k = 0; k < 128; k += 8) {
        ushort8 xv = *reinterpret_cast<const ushort8*>(x + k);
        ushort8 wv = *reinterpret_cast<const ushort8*>(ww + k);
#pragma unroll
        for (int u = 0; u < 8; ++u) acc += bf2f(xv[u]) * bf2f(wv[u]);
    }
    acc += __shfl_xor(acc, 1);
    acc += __shfl_xor(acc, 2);
    acc += __shfl_xor(acc, 4);
    if (part == 0) simxe[(size_t)r * NL + l] = acc + attnB[l];
}

// ---------------- bf16 MFMA GEMM (unchanged) ----------------
template<int MODE>
__global__ __launch_bounds__(256) void gemm_bf16(const u16* __restrict__ A, const u16* __restrict__ Bt,
                                                 void* __restrict__ Cout, const float* __restrict__ bias, int N) {
    __shared__ u16 ldsA[128 * 64];
    __shared__ u16 ldsB[128 * 64];
    const int t = threadIdx.x;
    const int lane = t & 63, w = t >> 6;
    const int wm = w >> 1, wn = w & 1;
    const int m0 = blockIdx.x * 128, n0 = blockIdx.y * 128;
    f32x4 acc[4][4] = {};
    for (int kt = 0; kt < 16; ++kt) {
        const int k0 = kt * 64;
#pragma unroll
        for (int i = 0; i < 4; ++i) {
            int chunk = i * 256 + t;
            int row = chunk >> 3, slot = chunk & 7;
            int srck = ((slot ^ (row & 7)) * 8);
            const u16* ga = A  + (size_t)(m0 + row) * 1024 + k0 + srck;
            const u16* gb = Bt + (size_t)(n0 + row) * 1024 + k0 + srck;
            u16* la = ldsA + (size_t)(i * 256 + w * 64) * 8;
            u16* lb = ldsB + (size_t)(i * 256 + w * 64) * 8;
            gld_lds16(ga, la);
            gld_lds16(gb, lb);
        }
        asm volatile("s_waitcnt vmcnt(0)" ::: "memory");
        __syncthreads();
#pragma unroll
        for (int kk = 0; kk < 2; ++kk) {
            bf16x8 a[4], b[4];
#pragma unroll
            for (int f = 0; f < 4; ++f) {
                int rowA = wm * 64 + f * 16 + (lane & 15);
                int slotA = (kk * 4 + (lane >> 4)) ^ (rowA & 7);
                a[f] = *reinterpret_cast<const bf16x8*>(ldsA + rowA * 64 + slotA * 8);
                int rowB = wn * 64 + f * 16 + (lane & 15);
                int slotB = (kk * 4 + (lane >> 4)) ^ (rowB & 7);
                b[f] = *reinterpret_cast<const bf16x8*>(ldsB + rowB * 64 + slotB * 8);
            }
#pragma unroll
            for (int fm = 0; fm < 4; ++fm)
#pragma unroll
                for (int fn = 0; fn < 4; ++fn)
                    acc[fm][fn] = mfma16(a[fm], b[fn], acc[fm][fn]);
        }
        __syncthreads();
    }
#pragma unroll
    for (int fm = 0; fm < 4; ++fm) {
#pragma unroll
        for (int fn = 0; fn < 4; ++fn) {
#pragma unroll
            for (int rr = 0; rr < 4; ++rr) {
                int m = m0 + wm * 64 + fm * 16 + (lane >> 4) * 4 + rr;
                int n = n0 + wn * 64 + fn * 16 + (lane & 15);
                float v = acc[fm][fn][rr];
                if (bias) v += bias[n];
                if (MODE == 0)      ((float*)Cout)[(size_t)m * N + n] = v;
                else if (MODE == 2) ((u16*)Cout)[(size_t)m * N + n] = f2bf(v);
                else if (MODE == 1)
                    ((float*)Cout)[((size_t)(m & 31) * NS + (m >> 5)) * NV + n] = v;
                else
                    ((u16*)Cout)[((size_t)(m & 31) * NS + (m >> 5)) * NV + n] = f2bf(v);
            }
        }
    }
}

// ---------------- persistent recurrence, fence-free MALL-coherent sync ----------------
// flagA lines: bar[0 + i*64], i<8   (role-A arrivals: 64/step, 8 per line)
// flagB lines: bar[512 + i*64], i<8 (role-B arrivals: 128/step, 16 per line)
__global__ __launch_bounds__(512) void recurrence4(
    const float* __restrict__ simxe, const u16* __restrict__ gxe,
    const u16* __restrict__ P, const u16* __restrict__ aw2t,
    const u16* __restrict__ whht, const u16* __restrict__ wiht,
    const float* __restrict__ b_ih, const float* __restrict__ b_hh,
    u16* __restrict__ g_glob, u16* __restrict__ hallx, int* __restrict__ bar)
{
    __shared__ __align__(16) char smem[155648];
    int* flagA = bar;
    int* flagB = bar + 512;
    const int blk = blockIdx.x, t = threadIdx.x;
    const int lane = t & 63, w = t >> 6;
    const int r16 = lane & 15, kg = lane >> 4;

    if (blk < RA_BLOCKS) {
        // =========== ROLE A: sim + softmax + g ===========
        int* myLine = flagA + ((blk >> 3) & 7) * 64;
        const int b = blk >> 1, half = blk & 1;
        u16*   W2T  = (u16*)smem;                    // [48][1032] bf16 = 99072
        u16*   Pl   = (u16*)(smem + 99072);          // [48][512] bf16 = 49152
        float* siml = (float*)(smem + 148224);       // [32][48] f32 = 6144
        float* wl   = (float*)(smem + 154368);       // 48 f32 (192B)
        u16*   gtmp = (u16*)(smem + 154560);         // 512 bf16 (1024B)
        for (int idx = t; idx < 48 * 1024; idx += 512) {
            int l = idx >> 10, k = idx & 1023;
            W2T[l * 1032 + k] = aw2t[idx];
        }
        for (int idx = t; idx < 48 * 512; idx += 512) {
            int l = idx >> 9, j = idx & 511;
            Pl[idx] = P[((size_t)(b * 48 + l)) * NH + half * 512 + j];
        }
        __syncthreads();

        for (int s = 0; s < NS; ++s) {
            float gxev = bf2f(gxe[((size_t)(s * 32 + b)) * NH + half * 512 + t]);  // h-independent, cached
            if (t == 0) waitsum(flagB, 128 * s);
            __syncthreads();
            const u16* hprev = hallx + (size_t)s * (NB * NH);
            // --- sim = h @ W2 (+ simxe via acc init): 6 waves
            if (w < 6) {
                const int mt = w & 1, nt = w >> 1;
                const int m0 = mt * 16, n0 = nt * 16;
                f32x4 acc0; f32x4 acc1 = {};
                const float* sxe = simxe + (size_t)(s * 32) * NL;
#pragma unroll
                for (int rr = 0; rr < 4; ++rr)
                    acc0[rr] = sxe[(m0 + kg * 4 + rr) * NL + n0 + r16];
                const u16* aB = hprev + (size_t)(m0 + r16) * NH + kg * 8;
                const u16* bP = W2T + (n0 + r16) * 1032 + kg * 8;
                bf16x8 A[16];
                LOAD16(A, aB);
                TIE16(A);
#pragma unroll
                for (int j = 0; j < 8; ++j) {
                    acc0 = mfma16(A[2*j],   *reinterpret_cast<const bf16x8*>(bP + j*64), acc0);
                    acc1 = mfma16(A[2*j+1], *reinterpret_cast<const bf16x8*>(bP + j*64 + 32), acc1);
                }
                const u16* aB2 = aB + 512;
                LOAD16(A, aB2);
                TIE16(A);
#pragma unroll
                for (int j = 0; j < 8; ++j) {
                    acc0 = mfma16(A[2*j],   *reinterpret_cast<const bf16x8*>(bP + 512 + j*64), acc0);
                    acc1 = mfma16(A[2*j+1], *reinterpret_cast<const bf16x8*>(bP + 512 + j*64 + 32), acc1);
                }
#pragma unroll
                for (int rr = 0; rr < 4; ++rr)
                    siml[(m0 + kg * 4 + rr) * NL + n0 + r16] = acc0[rr] + acc1[rr];
            }
            __syncthreads();
            // --- softmax over batch (col-wise), keep row b
            if (t < NL) {
                float m = -1e30f;
                for (int b2 = 0; b2 < NB; ++b2) m = fmaxf(m, siml[b2 * NL + t]);
                float den = 0.f;
                for (int b2 = 0; b2 < NB; ++b2) den += __expf(siml[b2 * NL + t] - m);
                wl[t] = __expf(siml[b * NL + t] - m) / den;
            }
            __syncthreads();
            // --- g slice -> gtmp
            {
                float acc = gxev;
#pragma unroll
                for (int l = 0; l < 48; ++l) acc += wl[l] * bf2f(Pl[l * 512 + t]);
                gtmp[t] = f2bf(fmaxf(acc, 0.f));
            }
            __syncthreads();
            if (t < 64) {
                uint4v v = *reinterpret_cast<const uint4v*>(gtmp + t * 8);
                st16_coh(g_glob + (size_t)b * NH + half * 512 + t * 8, v);
            }
            if (t == 0) bumpline(myLine);
        }
    } else {
        // =========== ROLE B: gh, gx, gates, h_new ===========
        int* myLine = flagB + (((blk - RA_BLOCKS) >> 4) & 7) * 64;
        const int c0 = (blk - RA_BLOCKS) * 8;
        u16*   Whh = (u16*)smem;                     // [32][1032] (rows 24..31 zero) 66048
        u16*   Wih = (u16*)(smem + 66048);           // 66048
        float* ghs = (float*)(smem + 132096);        // [2][32][32] f32 = 8192
        float* gxs = (float*)(smem + 140288);        // 8192
        u16*   htmp = (u16*)(smem + 148480);         // 256 bf16 (512B)
        for (int idx = t; idx < 32 * 1024; idx += 512) {
            int pr = idx >> 10, k = idx & 1023;
            u16 vh = 0, vi = 0;
            if (pr < 24) {
                size_t srow = (size_t)((pr >> 3) * 1024 + c0 + (pr & 7));
                vh = whht[srow * NH + k];
                vi = wiht[srow * NH + k];
            }
            Whh[pr * 1032 + k] = vh;
            Wih[pr * 1032 + k] = vi;
        }
        const int gb2 = (t & 255) >> 3, gcol = t & 7;
        const float bxr = b_ih[c0 + gcol], bxz = b_ih[1024 + c0 + gcol], bxn = b_ih[2048 + c0 + gcol];
        const float bhr = b_hh[c0 + gcol], bhz = b_hh[1024 + c0 + gcol], bhn = b_hh[2048 + c0 + gcol];
        __syncthreads();
        const int mt = (w >> 1) & 1, nt = w & 1, kh = w >> 2;
        const int m0 = mt * 16;

        for (int s = 0; s < NS; ++s) {
            if (t == 0) waitsum(flagB, 128 * s);
            __syncthreads();
            const u16* hprev = hallx + (size_t)s * (NB * NH);
            // issue coherent loads: gh A-fragments + the h_old scalar for the gate update
            const u16* aB = hprev + (size_t)(m0 + r16) * NH + kh * 512 + kg * 8;
            const u16* hp = hprev + (size_t)gb2 * NH + c0 + gcol;
            unsigned hv;
            asm volatile("global_load_ushort %0, %1, off sc0 sc1" : "=v"(hv) : "v"(hp));
            bf16x8 A[16];
            LOAD16(A, aB);
            TIE17(A, hv);
            {
                f32x4 acc0 = {}, acc1 = {};
                const u16* bP = Whh + (nt * 16 + r16) * 1032 + kh * 512 + kg * 8;
#pragma unroll
                for (int j = 0; j < 8; ++j) {
                    acc0 = mfma16(A[2*j],   *reinterpret_cast<const bf16x8*>(bP + j*64), acc0);
                    acc1 = mfma16(A[2*j+1], *reinterpret_cast<const bf16x8*>(bP + j*64 + 32), acc1);
                }
#pragma unroll
                for (int rr = 0; rr < 4; ++rr)
                    ghs[kh * 1024 + (m0 + kg * 4 + rr) * 32 + nt * 16 + r16] = acc0[rr] + acc1[rr];
            }
            if (t == 0) waitsum(flagA, 64 * (s + 1));
            __syncthreads();
            // --- gx
            {
                const u16* gB = g_glob + (size_t)(m0 + r16) * NH + kh * 512 + kg * 8;
                LOAD16(A, gB);
                TIE16(A);
                f32x4 acc0 = {}, acc1 = {};
                const u16* bP = Wih + (nt * 16 + r16) * 1032 + kh * 512 + kg * 8;
#pragma unroll
                for (int j = 0; j < 8; ++j) {
                    acc0 = mfma16(A[2*j],   *reinterpret_cast<const bf16x8*>(bP + j*64), acc0);
                    acc1 = mfma16(A[2*j+1], *reinterpret_cast<const bf16x8*>(bP + j*64 + 32), acc1);
                }
#pragma unroll
                for (int rr = 0; rr < 4; ++rr)
                    gxs[kh * 1024 + (m0 + kg * 4 + rr) * 32 + nt * 16 + r16] = acc0[rr] + acc1[rr];
            }
            __syncthreads();
            // --- gates + h_new
            if (t < 256) {
                float gxr = gxs[gb2 * 32 + gcol]      + gxs[1024 + gb2 * 32 + gcol]      + bxr;
                float gxz = gxs[gb2 * 32 + 8 + gcol]  + gxs[1024 + gb2 * 32 + 8 + gcol]  + bxz;
                float gxn = gxs[gb2 * 32 + 16 + gcol] + gxs[1024 + gb2 * 32 + 16 + gcol] + bxn;
                float ghr = ghs[gb2 * 32 + gcol]      + ghs[1024 + gb2 * 32 + gcol]      + bhr;
                float ghz = ghs[gb2 * 32 + 8 + gcol]  + ghs[1024 + gb2 * 32 + 8 + gcol]  + bhz;
                float ghn = ghs[gb2 * 32 + 16 + gcol] + ghs[1024 + gb2 * 32 + 16 + gcol] + bhn;
                float rg = 1.f / (1.f + __expf(-(gxr + ghr)));
                float zg = 1.f / (1.f + __expf(-(gxz + ghz)));
                float ng = tanhf(gxn + rg * ghn);
                float hold = bf2f((u16)hv);
                float hnew = (1.f - zg) * ng + zg * hold;
                htmp[t] = f2bf(hnew);
            }
            __syncthreads();
            if (t < 32) {
                uint4v v = *reinterpret_cast<const uint4v*>(htmp + t * 8);
                st16_coh(hallx + ((size_t)(s + 1) * NB + t) * NH + c0, v);
            }
            if (t == 0) bumpline(myLine);
        }
    }
}

// ---------------- log_softmax variants ----------------
__global__ __launch_bounds__(256) void logsoftmax_kernel(float* __restrict__ out) {
    __shared__ float red[8];
    float* row = out + (size_t)blockIdx.x * NV;
    int t = threadIdx.x;
    float m = -1e30f;
    for (int i = t; i < NV; i += 256) m = fmaxf(m, row[i]);
    for (int o = 32; o >= 1; o >>= 1) m = fmaxf(m, __shfl_xor(m, o));
    if ((t & 63) == 0) red[t >> 6] = m;
    __syncthreads();
    m = fmaxf(fmaxf(red[0], red[1]), fmaxf(red[2], red[3]));
    float sum = 0.f;
    for (int i = t; i < NV; i += 256) sum += __expf(row[i] - m);
    for (int o = 32; o >= 1; o >>= 1) sum += __shfl_xor(sum, o);
    if ((t & 63) == 0) red[4 + (t >> 6)] = sum;
    __syncthreads();
    sum = (red[4] + red[5]) + (red[6] + red[7]);
    float lse = m + __logf(sum);
    for (int i = t; i < NV; i += 256) row[i] = row[i] - lse;
}

__global__ __launch_bounds__(256) void logsoftmax_bf16(const u16* __restrict__ lg, float* __restrict__ out) {
    __shared__ __align__(16) u16 rowb[NV];   // 64000 B
    __shared__ float red[8];
    const u16* src = lg + (size_t)blockIdx.x * NV;
    float* dst = out + (size_t)blockIdx.x * NV;
    int t = threadIdx.x;
    for (int i = t; i < NV / 8; i += 256)
        ((ushort8*)rowb)[i] = ((const ushort8*)src)[i];
    __syncthreads();
    float m = -1e30f;
    for (int i = t; i < NV; i += 256) m = fmaxf(m, bf2f(rowb[i]));
    for (int o = 32; o >= 1; o >>= 1) m = fmaxf(m, __shfl_xor(m, o));
    if ((t & 63) == 0) red[t >> 6] = m;
    __syncthreads();
    m = fmaxf(fmaxf(red[0], red[1]), fmaxf(red[2], red[3]));
    float sum = 0.f;
    for (int i = t; i < NV; i += 256) sum += __expf(bf2f(rowb[i]) - m);
    for (int o = 32; o >= 1; o >>= 1) sum += __shfl_xor(sum, o);
    if ((t & 63) == 0) red[4 + (t >> 6)] = sum;
    __syncthreads();
    sum = (red[4] + red[5]) + (red[6] + red[7]);
    float lse = m + __logf(sum);
    for (int i = t; i < NV; i += 256) dst[i] = bf2f(rowb[i]) - lse;
}

extern "C" void kernel_launch(void* const* d_in, const int* in_sizes, int n_in,
                              void* d_out, int out_size, void* d_ws, size_t ws_size,
                              hipStream_t stream) {
    const int*   label = (const int*)  d_in[0];
    const float* inith = (const float*)d_in[1];
    const float* enc   = (const float*)d_in[2];
    const float* emb   = (const float*)d_in[3];
    const float* attnW = (const float*)d_in[4];
    const float* attnB = (const float*)d_in[5];
    const float* combW = (const float*)d_in[6];
    const float* combB = (const float*)d_in[7];
    const float* Wih   = (const float*)d_in[8];
    const float* Whh   = (const float*)d_in[9];
    const float* bih   = (const float*)d_in[10];
    const float* bhh   = (const float*)d_in[11];
    const float* outW  = (const float*)d_in[12];
    const float* outB  = (const float*)d_in[13];
    char* ws = (char*)d_ws;

    size_t BAR_OFF    = 0;                                // 4096
    size_t OUTWT_OFF  = 4096;
    size_t WHHT_OFF   = OUTWT_OFF + (size_t)NV*NH*2;
    size_t WIHT_OFF   = WHHT_OFF + (size_t)K3H*NH*2;
    size_t CW1T_OFF   = WIHT_OFF + (size_t)K3H*NH*2;
    size_t CW2T_OFF   = CW1T_OFF + (size_t)NH*NH*2;
    size_t AW2T_OFF   = CW2T_OFF + (size_t)NH*NH*2;
    size_t AW1T_OFF   = AW2T_OFF + (size_t)NL*NH*2;
    size_t XE_OFF     = AW2T_OFF + (size_t)NL*NH*4;
    size_t ENCB_OFF   = XE_OFF   + (size_t)NR*NE*2;
    size_t SIMXE_OFF  = ENCB_OFF + (size_t)NR*NH*2;
    size_t GXE_OFF    = SIMXE_OFF+ (size_t)NR*NL*4;
    size_t P_OFF      = GXE_OFF  + (size_t)NR*NH*2;
    size_t HALL_OFF   = P_OFF    + (size_t)NR*NH*2;       // hallx [49][B][H] bf16
    size_t GGLOB_OFF  = HALL_OFF + (size_t)(NS+1)*NB*NH*2;
    size_t LOGIT_OFF  = GGLOB_OFF+ (size_t)NB*NH*2;       // bf16 logits [NR][NV]
    size_t TOTAL_NEED = LOGIT_OFF+ (size_t)NR*NV*2;

    int*   bar   = (int*)(ws + BAR_OFF);
    u16*   outWT = (u16*)(ws + OUTWT_OFF);
    u16*   whht  = (u16*)(ws + WHHT_OFF);
    u16*   wiht  = (u16*)(ws + WIHT_OFF);
    u16*   cw1t  = (u16*)(ws + CW1T_OFF);
    u16*   cw2t  = (u16*)(ws + CW2T_OFF);
    u16*   aw2t  = (u16*)(ws + AW2T_OFF);
    u16*   aw1t  = (u16*)(ws + AW1T_OFF);
    u16*   xe    = (u16*)(ws + XE_OFF);
    u16*   encb  = (u16*)(ws + ENCB_OFF);
    float* simxe = (float*)(ws + SIMXE_OFF);
    u16*   gxe   = (u16*)(ws + GXE_OFF);
    u16*   Pb    = (u16*)(ws + P_OFF);
    u16*   hallx = (u16*)(ws + HALL_OFF);
    u16*   gglob = (u16*)(ws + GGLOB_OFF);
    u16*   logit = (u16*)(ws + LOGIT_OFF);

    hipMemsetAsync(bar, 0, 4096, stream);
    prep_inputs<<<2 * NR + NB, 256, 0, stream>>>(label, emb, enc, inith, xe, encb, hallx);

    transpose_cast<<<dim3(NV / 32, 32), 256, 0, stream>>>(outW, NH, NV, (char*)outWT, 1);
    transpose_cast<<<dim3(K3H / 32, 32), 256, 0, stream>>>(Whh, NH, K3H, (char*)whht, 1);
    transpose_cast<<<dim3(K3H / 32, 32), 256, 0, stream>>>(Wih, NH, K3H, (char*)wiht, 1);
    transpose_cast<<<dim3(NH / 32, 32), 256, 0, stream>>>(combW, NH, NH, (char*)cw1t, 1);
    transpose_cast<<<dim3(NH / 32, 32), 256, 0, stream>>>(combW + (size_t)NH * NH, NH, NH, (char*)cw2t, 1);
    transpose_cast<<<dim3(2, 32), 256, 0, stream>>>(attnW + (size_t)NH * NL, NH, NL, (char*)aw2t, 1);
    transpose_cast<<<dim3(2, 32), 256, 0, stream>>>(attnW, NH, NL, (char*)aw1t, 1);

    simxe2_kernel<<<NR, 384, 0, stream>>>(xe, aw1t, attnB, simxe);
    gemm_bf16<2><<<dim3(NR / 128, NH / 128), 256, 0, stream>>>(xe, cw2t, gxe, combB, NH);
    gemm_bf16<2><<<dim3(NR / 128, NH / 128), 256, 0, stream>>>(encb, cw1t, Pb, nullptr, NH);

    recurrence4<<<NBLK_R2, 512, 0, stream>>>(simxe, gxe, Pb, aw2t, whht, wiht,
                                             bih, bhh, gglob, hallx, bar);

    if (ws_size >= TOTAL_NEED) {
        gemm_bf16<3><<<dim3(NR / 128, NV / 128), 256, 0, stream>>>(hallx + (size_t)NB * NH, outWT, logit, outB, NV);
        logsoftmax_bf16<<<NR, 256, 0, stream>>>(logit, (float*)d_out);
    } else {
        gemm_bf16<1><<<dim3(NR / 128, NV / 128), 256, 0, stream>>>(hallx + (size_t)NB * NH, outWT, d_out, outB, NV);
        logsoftmax_kernel<<<NR, 256, 0, stream>>>((float*)d_out);
    }
}

// Round 5
// 1145.798 us; speedup vs baseline: 1.8609x; 1.0808x over previous
//
#include <hip/hip_runtime.h>

#define NB 32
#define NS 48
#define NL 48
#define NH 1024
#define NE 1024
#define NV 32000
#define NR (NS*NB)      // 1536
#define K3H 3072
#define RA_BLOCKS 64
#define RB_BLOCKS 128
#define NBLK_R2 (RA_BLOCKS + RB_BLOCKS)

typedef unsigned short u16;
typedef __bf16 bf16x8 __attribute__((ext_vector_type(8)));
typedef unsigned short ushort8 __attribute__((ext_vector_type(8)));
typedef float f32x4 __attribute__((ext_vector_type(4)));
typedef unsigned int uint4v __attribute__((ext_vector_type(4)));

__device__ __forceinline__ float bf2f(u16 x) {
    union { unsigned u; float f; } c; c.u = ((unsigned)x) << 16; return c.f;
}
__device__ __forceinline__ u16 f2bf(float f) {
    union { float f; unsigned u; } c; c.f = f;
    unsigned r = (c.u + 0x7FFFu + ((c.u >> 16) & 1u)) >> 16;
    return (u16)r;
}
__device__ __forceinline__ f32x4 mfma16(bf16x8 a, bf16x8 b, f32x4 c) {
    return __builtin_amdgcn_mfma_f32_16x16x32_bf16(a, b, c, 0, 0, 0);
}
__device__ __forceinline__ void gld_lds16(const void* g, void* l) {
    __builtin_amdgcn_global_load_lds((const __attribute__((address_space(1))) void*)g,
                                     (__attribute__((address_space(3))) void*)l, 16, 0, 0);
}

// ---- coherent store (write-through to IC, bypass L1/L2) ----
__device__ __forceinline__ void st16_coh(void* p, uint4v v) {
    asm volatile("global_store_dwordx4 %0, %1, off sc0 sc1" :: "v"(p), "v"(v) : "memory");
}

// ---- sync: single-line waiter poll ----
__device__ __forceinline__ void waitb(const int* line, int tgt) {
    if (tgt <= 0) return;
    int guard = 0; int v;
    for (;;) {
        asm volatile("global_load_dword %0, %1, off sc0 sc1\n\ts_waitcnt vmcnt(0)"
                     : "=v"(v) : "v"(line) : "memory");
        if (v >= tgt) return;
        __builtin_amdgcn_s_sleep(1);
        if (++guard > (1 << 20)) return;   // safety valve: wrong answer, not hang
    }
}
// ---- sync: producer arrive. 2-level counters; global-last broadcasts step to 24 lines ----
__device__ __forceinline__ void arrive2(int* cnt, int* superc, int* bcast, int lineMask, int val) {
    asm volatile("s_waitcnt vmcnt(0)" ::: "memory");   // my coherent stores are at IC
    int prev = __hip_atomic_fetch_add(cnt, 1, __ATOMIC_RELAXED, __HIP_MEMORY_SCOPE_AGENT);
    if ((prev & lineMask) == lineMask) {
        int p2 = __hip_atomic_fetch_add(superc, 1, __ATOMIC_RELAXED, __HIP_MEMORY_SCOPE_AGENT);
        if ((p2 & 7) == 7) {
#pragma unroll
            for (int i = 0; i < 24; ++i)
                asm volatile("global_store_dword %0, %1, off sc0 sc1"
                             :: "v"(bcast + i * 64), "v"(val) : "memory");
        }
    }
}

// ---------------- transpose + cast: dst[n][k] = src[k][n] ----------------
__global__ __launch_bounds__(256) void transpose_cast(const float* __restrict__ src, int K, int N,
                                                      char* __restrict__ dst, int bf16out) {
    __shared__ float tile[32][33];
    int k0 = blockIdx.y * 32, n0 = blockIdx.x * 32;
    int tx = threadIdx.x & 31, ty = threadIdx.x >> 5;
    for (int i = 0; i < 4; ++i) {
        int n = n0 + tx;
        float v = (n < N) ? src[(size_t)(k0 + ty + i*8) * N + n] : 0.f;
        tile[ty + i*8][tx] = v;
    }
    __syncthreads();
    for (int i = 0; i < 4; ++i) {
        int n = n0 + ty + i*8;
        int k = k0 + tx;
        if (n < N) {
            float v = tile[tx][ty + i*8];
            if (bf16out) ((u16*)dst)[(size_t)n * K + k] = f2bf(v);
            else         ((float*)dst)[(size_t)n * K + k] = v;
        }
    }
}

// ---------------- prep ----------------
__global__ __launch_bounds__(256) void prep_inputs(const int* __restrict__ label, const float* __restrict__ emb,
                                                   const float* __restrict__ enc, const float* __restrict__ inith,
                                                   u16* __restrict__ xe, u16* __restrict__ encb, u16* __restrict__ hallx) {
    int blk = blockIdx.x, t = threadIdx.x;
    if (blk < NR) {
        int s = blk >> 5, b = blk & 31;
        int lab = label[b * NS + s];
        const float* src = emb + (size_t)lab * NE;
        u16* dst = xe + (size_t)blk * NE;
        for (int i = t; i < NE; i += 256) { float v = src[i]; dst[i] = f2bf(v > 0.f ? v : 0.f); }
    } else if (blk < 2 * NR) {
        int r = blk - NR;
        const float* src = enc + (size_t)r * NH;
        u16* dst = encb + (size_t)r * NH;
        for (int i = t; i < NH; i += 256) dst[i] = f2bf(src[i]);
    } else {
        int b = blk - 2 * NR;
        const float* src = inith + (size_t)b * NH;
        u16* dst = hallx + (size_t)b * NH;   // slot 0 = h_{-1}
        for (int i = t; i < NH; i += 256) dst[i] = f2bf(src[i]);
    }
}

// ---------------- simxe ----------------
__global__ __launch_bounds__(384) void simxe2_kernel(const u16* __restrict__ xe, const u16* __restrict__ aw1t,
                                                     const float* __restrict__ attnB, float* __restrict__ simxe) {
    int r = blockIdx.x, t = threadIdx.x;
    int l = t >> 3, part = t & 7;
    const u16* x = xe + (size_t)r * 1024 + part * 128;
    const u16* ww = aw1t + (size_t)l * 1024 + part * 128;
    float acc = 0.f;
#pragma unroll
    for (int k = 0; k < 128; k += 8) {
        ushort8 xv = *reinterpret_cast<const ushort8*>(x + k);
        ushort8 wv = *reinterpret_cast<const ushort8*>(ww + k);
#pragma unroll
        for (int u = 0; u < 8; ++u) acc += bf2f(xv[u]) * bf2f(wv[u]);
    }
    acc += __shfl_xor(acc, 1);
    acc += __shfl_xor(acc, 2);
    acc += __shfl_xor(acc, 4);
    if (part == 0) simxe[(size_t)r * NL + l] = acc + attnB[l];
}

// ---------------- bf16 MFMA GEMM (unchanged) ----------------
template<int MODE>
__global__ __launch_bounds__(256) void gemm_bf16(const u16* __restrict__ A, const u16* __restrict__ Bt,
                                                 void* __restrict__ Cout, const float* __restrict__ bias, int N) {
    __shared__ u16 ldsA[128 * 64];
    __shared__ u16 ldsB[128 * 64];
    const int t = threadIdx.x;
    const int lane = t & 63, w = t >> 6;
    const int wm = w >> 1, wn = w & 1;
    const int m0 = blockIdx.x * 128, n0 = blockIdx.y * 128;
    f32x4 acc[4][4] = {};
    for (int kt = 0; kt < 16; ++kt) {
        const int k0 = kt * 64;
#pragma unroll
        for (int i = 0; i < 4; ++i) {
            int chunk = i * 256 + t;
            int row = chunk >> 3, slot = chunk & 7;
            int srck = ((slot ^ (row & 7)) * 8);
            const u16* ga = A  + (size_t)(m0 + row) * 1024 + k0 + srck;
            const u16* gb = Bt + (size_t)(n0 + row) * 1024 + k0 + srck;
            u16* la = ldsA + (size_t)(i * 256 + w * 64) * 8;
            u16* lb = ldsB + (size_t)(i * 256 + w * 64) * 8;
            gld_lds16(ga, la);
            gld_lds16(gb, lb);
        }
        asm volatile("s_waitcnt vmcnt(0)" ::: "memory");
        __syncthreads();
#pragma unroll
        for (int kk = 0; kk < 2; ++kk) {
            bf16x8 a[4], b[4];
#pragma unroll
            for (int f = 0; f < 4; ++f) {
                int rowA = wm * 64 + f * 16 + (lane & 15);
                int slotA = (kk * 4 + (lane >> 4)) ^ (rowA & 7);
                a[f] = *reinterpret_cast<const bf16x8*>(ldsA + rowA * 64 + slotA * 8);
                int rowB = wn * 64 + f * 16 + (lane & 15);
                int slotB = (kk * 4 + (lane >> 4)) ^ (rowB & 7);
                b[f] = *reinterpret_cast<const bf16x8*>(ldsB + rowB * 64 + slotB * 8);
            }
#pragma unroll
            for (int fm = 0; fm < 4; ++fm)
#pragma unroll
                for (int fn = 0; fn < 4; ++fn)
                    acc[fm][fn] = mfma16(a[fm], b[fn], acc[fm][fn]);
        }
        __syncthreads();
    }
#pragma unroll
    for (int fm = 0; fm < 4; ++fm) {
#pragma unroll
        for (int fn = 0; fn < 4; ++fn) {
#pragma unroll
            for (int rr = 0; rr < 4; ++rr) {
                int m = m0 + wm * 64 + fm * 16 + (lane >> 4) * 4 + rr;
                int n = n0 + wn * 64 + fn * 16 + (lane & 15);
                float v = acc[fm][fn][rr];
                if (bias) v += bias[n];
                if (MODE == 0)      ((float*)Cout)[(size_t)m * N + n] = v;
                else if (MODE == 2) ((u16*)Cout)[(size_t)m * N + n] = f2bf(v);
                else if (MODE == 1)
                    ((float*)Cout)[((size_t)(m & 31) * NS + (m >> 5)) * NV + n] = v;
                else
                    ((u16*)Cout)[((size_t)(m & 31) * NS + (m >> 5)) * NV + n] = f2bf(v);
            }
        }
    }
}

// ---------------- persistent recurrence v5 ----------------
// Data: producers store sc0sc1 (write-through to IC); consumers use NORMAL loads at
// per-step-rotated addresses (never cached earlier in this launch -> L2 miss -> IC -> fresh).
// Sync: 2-level producer counters; global-last broadcasts step to 24 lines; waiters poll 1 line.
// bar layout (ints): cntB[8 lines @64], cntA @512, superB @1024, superA @1088,
//                    bcastB @1152 (24 lines @64), bcastA @2688 (24 lines @64)
__global__ __launch_bounds__(512) void recurrence5(
    const float* __restrict__ simxe, const u16* __restrict__ gxe,
    const u16* __restrict__ P, const u16* __restrict__ aw2t,
    const u16* __restrict__ whht, const u16* __restrict__ wiht,
    const float* __restrict__ b_ih, const float* __restrict__ b_hh,
    u16* __restrict__ g_rot, u16* __restrict__ hallx, int* __restrict__ bar)
{
    __shared__ __align__(16) char smem[155776];
    int* cntB   = bar;
    int* cntA   = bar + 512;
    int* superB = bar + 1024;
    int* superA = bar + 1088;
    int* bcastB = bar + 1152;
    int* bcastA = bar + 2688;
    const int blk = blockIdx.x, t = threadIdx.x;
    const int lane = t & 63, w = t >> 6;
    const int r16 = lane & 15, kg = lane >> 4;

    if (blk < RA_BLOCKS) {
        // =========== ROLE A: sim + softmax-over-batch + g ===========
        int* myB = bcastB + (blk % 24) * 64;
        const int b = blk >> 1, half = blk & 1;
        u16*   W2T  = (u16*)smem;                    // [48][1032] bf16 = 99072
        u16*   Pl   = (u16*)(smem + 99072);          // [48][512] bf16 = 49152
        float* siml = (float*)(smem + 148224);       // [32][49] f32 = 6272
        float* wl   = (float*)(smem + 154496);       // 48 f32
        u16*   gtmp = (u16*)(smem + 154752);         // 512 bf16 = 1024
        for (int idx = t; idx < 48 * 1024; idx += 512) {
            int l = idx >> 10, k = idx & 1023;
            W2T[l * 1032 + k] = aw2t[idx];
        }
        for (int idx = t; idx < 48 * 512; idx += 512) {
            int l = idx >> 9, j = idx & 511;
            Pl[idx] = P[((size_t)(b * 48 + l)) * NH + half * 512 + j];
        }
        __syncthreads();

        for (int s = 0; s < NS; ++s) {
            float gxev = bf2f(gxe[((size_t)(s * 32 + b)) * NH + half * 512 + t]);  // h-independent
            if (t == 0) waitb(myB, s);
            __syncthreads();
            const u16* hprev = hallx + (size_t)s * (NB * NH);
            // --- sim = h @ W2 (+ simxe acc init): 6 waves; NORMAL loads (L2 path)
            if (w < 6) {
                const int mt = w & 1, nt = w >> 1;
                const int m0 = mt * 16, n0 = nt * 16;
                f32x4 acc0; f32x4 acc1 = {};
                const float* sxe = simxe + (size_t)(s * 32) * NL;
#pragma unroll
                for (int rr = 0; rr < 4; ++rr)
                    acc0[rr] = sxe[(m0 + kg * 4 + rr) * NL + n0 + r16];
                const u16* aP = hprev + (size_t)(m0 + r16) * NH + kg * 8;
                const u16* bP = W2T + (n0 + r16) * 1032 + kg * 8;
#pragma unroll
                for (int k = 0; k < 1024; k += 64) {
                    acc0 = mfma16(*reinterpret_cast<const bf16x8*>(aP + k),
                                  *reinterpret_cast<const bf16x8*>(bP + k), acc0);
                    acc1 = mfma16(*reinterpret_cast<const bf16x8*>(aP + k + 32),
                                  *reinterpret_cast<const bf16x8*>(bP + k + 32), acc1);
                }
#pragma unroll
                for (int rr = 0; rr < 4; ++rr)
                    siml[(m0 + kg * 4 + rr) * 49 + n0 + r16] = acc0[rr] + acc1[rr];
            }
            __syncthreads();
            // --- softmax over batch, parallel: 8 lanes per column l
            if (t < 384) {
                int l = t >> 3, p = t & 7;
                float v0 = siml[(p * 4 + 0) * 49 + l];
                float v1 = siml[(p * 4 + 1) * 49 + l];
                float v2 = siml[(p * 4 + 2) * 49 + l];
                float v3 = siml[(p * 4 + 3) * 49 + l];
                float m = fmaxf(fmaxf(v0, v1), fmaxf(v2, v3));
                m = fmaxf(m, __shfl_xor(m, 1));
                m = fmaxf(m, __shfl_xor(m, 2));
                m = fmaxf(m, __shfl_xor(m, 4));
                float den = __expf(v0 - m) + __expf(v1 - m) + __expf(v2 - m) + __expf(v3 - m);
                den += __shfl_xor(den, 1);
                den += __shfl_xor(den, 2);
                den += __shfl_xor(den, 4);
                if (p == (b >> 2)) {
                    int bi = b & 3;
                    float vb = bi == 0 ? v0 : bi == 1 ? v1 : bi == 2 ? v2 : v3;
                    wl[l] = __expf(vb - m) / den;
                }
            }
            __syncthreads();
            // --- g slice = relu(gxe + sum_l wl[l]*P[l][:]) -> gtmp
            {
                float acc = gxev;
#pragma unroll
                for (int l = 0; l < 48; ++l) acc += wl[l] * bf2f(Pl[l * 512 + t]);
                gtmp[t] = f2bf(fmaxf(acc, 0.f));
            }
            __syncthreads();
            if (t < 64) {
                uint4v v = *reinterpret_cast<const uint4v*>(gtmp + t * 8);
                st16_coh(g_rot + (size_t)s * (NB * NH) + (size_t)b * NH + half * 512 + t * 8, v);
            }
            if (t == 0) arrive2(cntA + (blk & 7) * 64, superA, bcastA, 7, s + 1);
        }
    } else {
        // =========== ROLE B: gh, gx, gates, h_new ===========
        const int rb = blk - RA_BLOCKS;
        int* myB = bcastB + (rb % 24) * 64;
        int* myA = bcastA + (rb % 24) * 64;
        const int c0 = rb * 8;
        u16*   Whh = (u16*)smem;                     // [32][1032] (rows 24..31 zero) 66048
        u16*   Wih = (u16*)(smem + 66048);           // 66048
        float* ghs = (float*)(smem + 132096);        // [2][32][32] f32 = 8192
        float* gxs = (float*)(smem + 140288);        // 8192
        u16*   htmp = (u16*)(smem + 148480);         // 256 bf16
        for (int idx = t; idx < 32 * 1024; idx += 512) {
            int pr = idx >> 10, k = idx & 1023;
            u16 vh = 0, vi = 0;
            if (pr < 24) {
                size_t srow = (size_t)((pr >> 3) * 1024 + c0 + (pr & 7));
                vh = whht[srow * NH + k];
                vi = wiht[srow * NH + k];
            }
            Whh[pr * 1032 + k] = vh;
            Wih[pr * 1032 + k] = vi;
        }
        const int gb2 = (t & 255) >> 3, gcol = t & 7;
        const float bxr = b_ih[c0 + gcol], bxz = b_ih[1024 + c0 + gcol], bxn = b_ih[2048 + c0 + gcol];
        const float bhr = b_hh[c0 + gcol], bhz = b_hh[1024 + c0 + gcol], bhn = b_hh[2048 + c0 + gcol];
        __syncthreads();
        const int mt = (w >> 1) & 1, nt = w & 1, kh = w >> 2;
        const int m0 = mt * 16;

        for (int s = 0; s < NS; ++s) {
            if (t == 0) waitb(myB, s);
            __syncthreads();
            const u16* hprev = hallx + (size_t)s * (NB * NH);
            const u16* gcur  = g_rot + (size_t)s * (NB * NH);
            float hold = bf2f(hprev[(size_t)gb2 * NH + c0 + gcol]);   // for gate blend
            // --- gh = h @ W_hh slice; NORMAL loads
            {
                f32x4 acc0 = {}, acc1 = {};
                const u16* aP = hprev + (size_t)(m0 + r16) * NH + kh * 512 + kg * 8;
                const u16* bP = Whh + (nt * 16 + r16) * 1032 + kh * 512 + kg * 8;
#pragma unroll
                for (int k = 0; k < 512; k += 64) {
                    acc0 = mfma16(*reinterpret_cast<const bf16x8*>(aP + k),
                                  *reinterpret_cast<const bf16x8*>(bP + k), acc0);
                    acc1 = mfma16(*reinterpret_cast<const bf16x8*>(aP + k + 32),
                                  *reinterpret_cast<const bf16x8*>(bP + k + 32), acc1);
                }
#pragma unroll
                for (int rr = 0; rr < 4; ++rr)
                    ghs[kh * 1024 + (m0 + kg * 4 + rr) * 32 + nt * 16 + r16] = acc0[rr] + acc1[rr];
            }
            if (t == 0) waitb(myA, s + 1);
            __syncthreads();
            // --- gx = g @ W_ih slice; NORMAL loads from rotated g
            {
                f32x4 acc0 = {}, acc1 = {};
                const u16* aP = gcur + (size_t)(m0 + r16) * NH + kh * 512 + kg * 8;
                const u16* bP = Wih + (nt * 16 + r16) * 1032 + kh * 512 + kg * 8;
#pragma unroll
                for (int k = 0; k < 512; k += 64) {
                    acc0 = mfma16(*reinterpret_cast<const bf16x8*>(aP + k),
                                  *reinterpret_cast<const bf16x8*>(bP + k), acc0);
                    acc1 = mfma16(*reinterpret_cast<const bf16x8*>(aP + k + 32),
                                  *reinterpret_cast<const bf16x8*>(bP + k + 32), acc1);
                }
#pragma unroll
                for (int rr = 0; rr < 4; ++rr)
                    gxs[kh * 1024 + (m0 + kg * 4 + rr) * 32 + nt * 16 + r16] = acc0[rr] + acc1[rr];
            }
            __syncthreads();
            // --- gates + h_new
            if (t < 256) {
                float gxr = gxs[gb2 * 32 + gcol]      + gxs[1024 + gb2 * 32 + gcol]      + bxr;
                float gxz = gxs[gb2 * 32 + 8 + gcol]  + gxs[1024 + gb2 * 32 + 8 + gcol]  + bxz;
                float gxn = gxs[gb2 * 32 + 16 + gcol] + gxs[1024 + gb2 * 32 + 16 + gcol] + bxn;
                float ghr = ghs[gb2 * 32 + gcol]      + ghs[1024 + gb2 * 32 + gcol]      + bhr;
                float ghz = ghs[gb2 * 32 + 8 + gcol]  + ghs[1024 + gb2 * 32 + 8 + gcol]  + bhz;
                float ghn = ghs[gb2 * 32 + 16 + gcol] + ghs[1024 + gb2 * 32 + 16 + gcol] + bhn;
                float rg = 1.f / (1.f + __expf(-(gxr + ghr)));
                float zg = 1.f / (1.f + __expf(-(gxz + ghz)));
                float ng = tanhf(gxn + rg * ghn);
                float hnew = (1.f - zg) * ng + zg * hold;
                htmp[t] = f2bf(hnew);
            }
            __syncthreads();
            if (t < 32) {
                uint4v v = *reinterpret_cast<const uint4v*>(htmp + t * 8);
                st16_coh(hallx + ((size_t)(s + 1) * NB + t) * NH + c0, v);
            }
            if (t == 0) arrive2(cntB + (rb & 7) * 64, superB, bcastB, 15, s + 1);
        }
    }
}

// ---------------- log_softmax variants ----------------
__global__ __launch_bounds__(256) void logsoftmax_kernel(float* __restrict__ out) {
    __shared__ float red[8];
    float* row = out + (size_t)blockIdx.x * NV;
    int t = threadIdx.x;
    float m = -1e30f;
    for (int i = t; i < NV; i += 256) m = fmaxf(m, row[i]);
    for (int o = 32; o >= 1; o >>= 1) m = fmaxf(m, __shfl_xor(m, o));
    if ((t & 63) == 0) red[t >> 6] = m;
    __syncthreads();
    m = fmaxf(fmaxf(red[0], red[1]), fmaxf(red[2], red[3]));
    float sum = 0.f;
    for (int i = t; i < NV; i += 256) sum += __expf(row[i] - m);
    for (int o = 32; o >= 1; o >>= 1) sum += __shfl_xor(sum, o);
    if ((t & 63) == 0) red[4 + (t >> 6)] = sum;
    __syncthreads();
    sum = (red[4] + red[5]) + (red[6] + red[7]);
    float lse = m + __logf(sum);
    for (int i = t; i < NV; i += 256) row[i] = row[i] - lse;
}

__global__ __launch_bounds__(256) void logsoftmax_bf16(const u16* __restrict__ lg, float* __restrict__ out) {
    __shared__ __align__(16) u16 rowb[NV];   // 64000 B
    __shared__ float red[8];
    const u16* src = lg + (size_t)blockIdx.x * NV;
    float* dst = out + (size_t)blockIdx.x * NV;
    int t = threadIdx.x;
    for (int i = t; i < NV / 8; i += 256)
        ((ushort8*)rowb)[i] = ((const ushort8*)src)[i];
    __syncthreads();
    float m = -1e30f;
    for (int i = t; i < NV; i += 256) m = fmaxf(m, bf2f(rowb[i]));
    for (int o = 32; o >= 1; o >>= 1) m = fmaxf(m, __shfl_xor(m, o));
    if ((t & 63) == 0) red[t >> 6] = m;
    __syncthreads();
    m = fmaxf(fmaxf(red[0], red[1]), fmaxf(red[2], red[3]));
    float sum = 0.f;
    for (int i = t; i < NV; i += 256) sum += __expf(bf2f(rowb[i]) - m);
    for (int o = 32; o >= 1; o >>= 1) sum += __shfl_xor(sum, o);
    if ((t & 63) == 0) red[4 + (t >> 6)] = sum;
    __syncthreads();
    sum = (red[4] + red[5]) + (red[6] + red[7]);
    float lse = m + __logf(sum);
    for (int i = t; i < NV; i += 256) dst[i] = bf2f(rowb[i]) - lse;
}

extern "C" void kernel_launch(void* const* d_in, const int* in_sizes, int n_in,
                              void* d_out, int out_size, void* d_ws, size_t ws_size,
                              hipStream_t stream) {
    const int*   label = (const int*)  d_in[0];
    const float* inith = (const float*)d_in[1];
    const float* enc   = (const float*)d_in[2];
    const float* emb   = (const float*)d_in[3];
    const float* attnW = (const float*)d_in[4];
    const float* attnB = (const float*)d_in[5];
    const float* combW = (const float*)d_in[6];
    const float* combB = (const float*)d_in[7];
    const float* Wih   = (const float*)d_in[8];
    const float* Whh   = (const float*)d_in[9];
    const float* bih   = (const float*)d_in[10];
    const float* bhh   = (const float*)d_in[11];
    const float* outW  = (const float*)d_in[12];
    const float* outB  = (const float*)d_in[13];
    char* ws = (char*)d_ws;

    size_t BAR_OFF    = 0;                                // 32768 (flag lines)
    size_t OUTWT_OFF  = 32768;
    size_t WHHT_OFF   = OUTWT_OFF + (size_t)NV*NH*2;
    size_t WIHT_OFF   = WHHT_OFF + (size_t)K3H*NH*2;
    size_t CW1T_OFF   = WIHT_OFF + (size_t)K3H*NH*2;
    size_t CW2T_OFF   = CW1T_OFF + (size_t)NH*NH*2;
    size_t AW2T_OFF   = CW2T_OFF + (size_t)NH*NH*2;
    size_t AW1T_OFF   = AW2T_OFF + (size_t)NL*NH*2;
    size_t XE_OFF     = AW2T_OFF + (size_t)NL*NH*4;
    size_t ENCB_OFF   = XE_OFF   + (size_t)NR*NE*2;
    size_t SIMXE_OFF  = ENCB_OFF + (size_t)NR*NH*2;
    size_t GXE_OFF    = SIMXE_OFF+ (size_t)NR*NL*4;
    size_t P_OFF      = GXE_OFF  + (size_t)NR*NH*2;
    size_t HALL_OFF   = P_OFF    + (size_t)NR*NH*2;       // hallx [49][B][H] bf16
    size_t GROT_OFF   = HALL_OFF + (size_t)(NS+1)*NB*NH*2; // g rotated [48][B][H] bf16 = 3MB
    size_t LOGIT_OFF  = GROT_OFF + (size_t)NS*NB*NH*2;    // bf16 logits [NR][NV]
    size_t TOTAL_NEED = LOGIT_OFF+ (size_t)NR*NV*2;

    int*   bar   = (int*)(ws + BAR_OFF);
    u16*   outWT = (u16*)(ws + OUTWT_OFF);
    u16*   whht  = (u16*)(ws + WHHT_OFF);
    u16*   wiht  = (u16*)(ws + WIHT_OFF);
    u16*   cw1t  = (u16*)(ws + CW1T_OFF);
    u16*   cw2t  = (u16*)(ws + CW2T_OFF);
    u16*   aw2t  = (u16*)(ws + AW2T_OFF);
    u16*   aw1t  = (u16*)(ws + AW1T_OFF);
    u16*   xe    = (u16*)(ws + XE_OFF);
    u16*   encb  = (u16*)(ws + ENCB_OFF);
    float* simxe = (float*)(ws + SIMXE_OFF);
    u16*   gxe   = (u16*)(ws + GXE_OFF);
    u16*   Pb    = (u16*)(ws + P_OFF);
    u16*   hallx = (u16*)(ws + HALL_OFF);
    u16*   grot  = (u16*)(ws + GROT_OFF);
    u16*   logit = (u16*)(ws + LOGIT_OFF);

    hipMemsetAsync(bar, 0, 32768, stream);
    prep_inputs<<<2 * NR + NB, 256, 0, stream>>>(label, emb, enc, inith, xe, encb, hallx);

    transpose_cast<<<dim3(NV / 32, 32), 256, 0, stream>>>(outW, NH, NV, (char*)outWT, 1);
    transpose_cast<<<dim3(K3H / 32, 32), 256, 0, stream>>>(Whh, NH, K3H, (char*)whht, 1);
    transpose_cast<<<dim3(K3H / 32, 32), 256, 0, stream>>>(Wih, NH, K3H, (char*)wiht, 1);
    transpose_cast<<<dim3(NH / 32, 32), 256, 0, stream>>>(combW, NH, NH, (char*)cw1t, 1);
    transpose_cast<<<dim3(NH / 32, 32), 256, 0, stream>>>(combW + (size_t)NH * NH, NH, NH, (char*)cw2t, 1);
    transpose_cast<<<dim3(2, 32), 256, 0, stream>>>(attnW + (size_t)NH * NL, NH, NL, (char*)aw2t, 1);
    transpose_cast<<<dim3(2, 32), 256, 0, stream>>>(attnW, NH, NL, (char*)aw1t, 1);

    simxe2_kernel<<<NR, 384, 0, stream>>>(xe, aw1t, attnB, simxe);
    gemm_bf16<2><<<dim3(NR / 128, NH / 128), 256, 0, stream>>>(xe, cw2t, gxe, combB, NH);
    gemm_bf16<2><<<dim3(NR / 128, NH / 128), 256, 0, stream>>>(encb, cw1t, Pb, nullptr, NH);

    recurrence5<<<NBLK_R2, 512, 0, stream>>>(simxe, gxe, Pb, aw2t, whht, wiht,
                                             bih, bhh, grot, hallx, bar);

    if (ws_size >= TOTAL_NEED) {
        gemm_bf16<3><<<dim3(NR / 128, NV / 128), 256, 0, stream>>>(hallx + (size_t)NB * NH, outWT, logit, outB, NV);
        logsoftmax_bf16<<<NR, 256, 0, stream>>>(logit, (float*)d_out);
    } else {
        gemm_bf16<1><<<dim3(NR / 128, NV / 128), 256, 0, stream>>>(hallx + (size_t)NB * NH, outWT, d_out, outB, NV);
        logsoftmax_kernel<<<NR, 256, 0, stream>>>((float*)d_out);
    }
}